// Round 13
// baseline (891.724 us; speedup 1.0000x reference)
//
#include <hip/hip_runtime.h>
#include <hip/hip_bf16.h>
#include <math.h>

#define Bb 16
#define DIN 16
#define LL 4096
#define HH 256
#define NN2 32
#define NLAY 4
#define HN (HH*NN2)
#define BN 32          // mm l-tile

typedef __attribute__((ext_vector_type(8))) short short8;
typedef __attribute__((ext_vector_type(4))) short short4v;
typedef __attribute__((ext_vector_type(4))) float f32x4;
typedef unsigned short u16;

__device__ inline u16 f2bf(float f) {
  unsigned int x = __float_as_uint(f);
  unsigned int r = x + 0x7FFFu + ((x >> 16) & 1u);   // RNE
  return (u16)(r >> 16);
}
__device__ inline float bf2f(u16 u) {
  return __uint_as_float(((unsigned int)u) << 16);
}
__device__ inline unsigned int packsplit(float v) {
  u16 hi = f2bf(v);
  u16 lo = f2bf(v - bf2f(hi));
  return (((unsigned int)hi) << 16) | lo;
}
// v_cvt_pk_bf16_f32: low16 = bf16(a), high16 = bf16(b), RNE
__device__ inline unsigned int cvtpk(float a, float b) {
  unsigned int r;
  asm("v_cvt_pk_bf16_f32 %0, %1, %2" : "=v"(r) : "v"(a), "v"(b));
  return r;
}
// LDS fragment loader: 4 u16 at p, 4 u16 at p+16 (k and k+16 halves)
__device__ inline short8 ld8(const u16* p) {
  short4v a = *(const short4v*)p;
  short4v b = *(const short4v*)(p + 16);
  return __builtin_shufflevector(a, b, 0, 1, 2, 3, 4, 5, 6, 7);
}
// fragment-major index for basis matrices: m in 0..5 (Th,Tl,Mh,Ml,Eh,El)
__device__ inline size_t fidx(int h, int m, int row, int col) {
  int wv = row >> 4, row16 = row & 15;
  int kh = col >> 5, c5 = col & 31;
  int lane = ((c5 & 15) >> 2) * 16 + row16;
  int j = (((c5 >> 4) & 1) << 2) | (c5 & 3);
  return ((((((size_t)h * 6 + m) * 4 + wv) * 2 + kh) * 64 + lane) << 3) + j;
}

// ---------------- encoder ----------------
__global__ __launch_bounds__(256) void enc_kernel(const float* __restrict__ x,
    const float* __restrict__ ew, const float* __restrict__ eb,
    float* __restrict__ hbuf) {
  int blk = blockIdx.x;
  int tile = blk & 15;
  int h = (blk >> 4) & (HH - 1);
  int b = blk >> 12;
  int l = tile * 256 + threadIdx.x;
  const float* xb = x + (size_t)b * DIN * LL + l;
  float acc = eb[h];
  #pragma unroll
  for (int i = 0; i < DIN; ++i)
    acc = fmaf(xb[(size_t)i * LL], ew[i * HH + h], acc);
  hbuf[((size_t)(b * HH + h)) * LL + l] = acc;
}

// ---------------- prep: basis (blocks 0..255) + W pack (blocks 256..511) ----------------
__global__ __launch_bounds__(256) void prep_kernel(
    const float* __restrict__ log_dt, const float* __restrict__ Are,
    const float* __restrict__ Aim, const float* __restrict__ Cre,
    const float* __restrict__ Cim, float* __restrict__ w64,
    u16* __restrict__ Bf, const float* __restrict__ W,
    unsigned int* __restrict__ Wp) {
  int t = threadIdx.x;
  if (blockIdx.x >= HH) {
    // ---- wpack: fragment-major Wp[wv][ks][di][lane][8] ----
    int idx = (blockIdx.x - HH) * 256 + t;
    int j = idx & 7;
    int lane = (idx >> 3) & 63;
    int di = (idx >> 9) & 3;
    int ks = (idx >> 11) & 7;
    int wv = idx >> 14;
    int row16 = lane & 15, kgrp = lane >> 4;
    int d = wv * 64 + di * 16 + row16;
    int hcol = ks * 32 + kgrp * 4 + (j & 3) + ((j >> 2) << 4);
    Wp[idx] = packsplit(W[hcol * HH + d]);
    return;
  }
  // ---- basis: T/M/E fragment-major + w64 ----
  __shared__ float K_l[64];
  int h = blockIdx.x;
  if (t < 32) {
    int n = t;
    int idx = h * 32 + n;
    float dt = expf(log_dt[h]);
    float ar = -expf(Are[idx]);
    float ai = Aim[idx];
    float er = expf(ar * dt);
    float wr = er * cosf(ai * dt);
    float wi = er * sinf(ai * dt);
    float nr = wr - 1.f, ni = wi;
    float inv = 1.f / (ar * ar + ai * ai);
    float qr = (nr * ar + ni * ai) * inv;
    float qi = (ni * ar - nr * ai) * inv;
    float crv = Cre[idx], civ = Cim[idx];
    float cr = 2.f * (crv * qr - civ * qi);
    float ci = 2.f * (crv * qi + civ * qr);
    // w^64 for the scan
    float pr = wr, pi = wi;
    #pragma unroll
    for (int q = 0; q < 6; ++q) {
      float t0 = pr * pr - pi * pi;
      pi = 2.f * pr * pi;
      pr = t0;
    }
    w64[idx] = pr;
    w64[HN + idx] = pi;
    // M, E, K
    float vr = 1.f, vi = 0.f;
    for (int m = 0; m <= 64; ++m) {
      float e = cr * vr - ci * vi;
      float f = -(cr * vi + ci * vr);
      float s = e;
      s += __shfl_xor(s, 1); s += __shfl_xor(s, 2); s += __shfl_xor(s, 4);
      s += __shfl_xor(s, 8); s += __shfl_xor(s, 16);
      if (m <= 63) {
        if (n == 0) K_l[m] = s;
        int i = 63 - m;
        u16 hr = f2bf(vr);
        Bf[fidx(h, 2, 2 * n, i)] = hr;
        Bf[fidx(h, 3, 2 * n, i)] = f2bf(vr - bf2f(hr));
        u16 hi2 = f2bf(vi);
        Bf[fidx(h, 2, 2 * n + 1, i)] = hi2;
        Bf[fidx(h, 3, 2 * n + 1, i)] = f2bf(vi - bf2f(hi2));
      }
      if (m >= 1) {
        int row = m - 1;
        u16 he = f2bf(e);
        Bf[fidx(h, 4, row, 2 * n)] = he;
        Bf[fidx(h, 5, row, 2 * n)] = f2bf(e - bf2f(he));
        u16 hf = f2bf(f);
        Bf[fidx(h, 4, row, 2 * n + 1)] = hf;
        Bf[fidx(h, 5, row, 2 * n + 1)] = f2bf(f - bf2f(hf));
      }
      float nvr = vr * wr - vi * wi;
      float nvi = vr * wi + vi * wr;
      vr = nvr; vi = nvi;
    }
  }
  __syncthreads();
  #pragma unroll
  for (int p = 0; p < 16; ++p) {
    int id = p * 256 + t;
    int j = id >> 6, i = id & 63;
    float kv = (j >= i) ? K_l[j - i] : 0.f;
    u16 hi = f2bf(kv);
    Bf[fidx(h, 0, j, i)] = hi;
    Bf[fidx(h, 1, j, i)] = f2bf(kv - bf2f(hi));
  }
}

// ---------------- MFMA SSM v4: persistent-h — one block per (h, b-group of 4) ----------------
// Fragments/multipliers loaded once, reused across 4 batches. Loop body identical to R10.
__global__ __launch_bounds__(256, 4) void s4_mfma_kernel(
    const float* __restrict__ zg, const float* __restrict__ w64,
    const float* __restrict__ Dvec, const u16* __restrict__ Bf,
    unsigned int* __restrict__ gout) {
  __shared__ u16 zh[64 * 68], zl[64 * 68];   // z planes [chunk][i], pad 68
  __shared__ float stT[64 * 68];             // Phase-A ends transposed; aliased later
  u16* sh = (u16*)stT;
  u16* sl = sh + 64 * 68;
  unsigned int* packbuf = (unsigned int*)stT;
  int bid = blockIdx.x;
  int h = bid & (HH - 1);
  int bgrp = bid >> 8;                       // 0..3
  int t = threadIdx.x;
  int wv = t >> 6, lane = t & 63, row16 = lane & 15, kgrp = lane >> 4;
  // hoisted per-h state: T/M fragments, scan multipliers, D (reused for 4 batches)
  const u16* BfH = Bf + (size_t)h * (6 * 4 * 2 * 64 * 8);
  #define LDF(m, kh) (*(const short8*)(BfH + (((m) * 4 + wv) * 2 + (kh)) * 512 + lane * 8))
  short8 fTh0 = LDF(0, 0), fTh1 = LDF(0, 1);
  short8 fTl0 = LDF(1, 0), fTl1 = LDF(1, 1);
  short8 fMh0 = LDF(2, 0), fMh1 = LDF(2, 1);
  short8 fMl0 = LDF(3, 0), fMl1 = LDF(3, 1);
  float pr0[8], pi0[8];
  #pragma unroll
  for (int k = 0; k < 8; ++k) {
    pr0[k] = w64[h * 32 + wv * 8 + k];
    pi0[k] = w64[HN + h * 32 + wv * 8 + k];
  }
  float Dh = Dvec[h];
  int c0 = t >> 2, i0 = (t & 3) * 16;
  for (int bi = 0; bi < 4; ++bi) {
    size_t bh = (size_t)(bgrp * 4 + bi) * HH + h;
    const float* zrow = zg + bh * LL;
    {
      const float4* zsrc = (const float4*)(zrow + c0 * 64 + i0);
      #pragma unroll
      for (int q = 0; q < 4; ++q) {
        float4 v = zsrc[q];
        unsigned int hp0 = cvtpk(v.x, v.y);
        unsigned int hp1 = cvtpk(v.z, v.w);
        float r0 = v.x - __uint_as_float(hp0 << 16);
        float r1 = v.y - __uint_as_float(hp0 & 0xFFFF0000u);
        float r2 = v.z - __uint_as_float(hp1 << 16);
        float r3 = v.w - __uint_as_float(hp1 & 0xFFFF0000u);
        unsigned int lp0 = cvtpk(r0, r1);
        unsigned int lp1 = cvtpk(r2, r3);
        int base = c0 * 68 + i0 + q * 4;
        *(unsigned int*)&zh[base] = hp0;
        *(unsigned int*)&zh[base + 2] = hp1;
        *(unsigned int*)&zl[base] = lp0;
        *(unsigned int*)&zl[base + 2] = lp1;
      }
    }
    __syncthreads();                                       // B1
    f32x4 y[4];
    // ---- Phase A: S_end = M@Z (stT transposed) and y = T@Z, shared z frags ----
    #pragma unroll
    for (int ct = 0; ct < 4; ++ct) {
      f32x4 aS = (f32x4){0.f, 0.f, 0.f, 0.f};
      f32x4 aY = (f32x4){0.f, 0.f, 0.f, 0.f};
      int cc = ct * 16 + row16;
      #pragma unroll
      for (int kh = 0; kh < 2; ++kh) {
        int kb = kh * 32 + kgrp * 4;
        short8 Bh = ld8(&zh[cc * 68 + kb]);
        short8 Bl = ld8(&zl[cc * 68 + kb]);
        short8 Ah = kh ? fMh1 : fMh0;
        short8 Al = kh ? fMl1 : fMl0;
        aS = __builtin_amdgcn_mfma_f32_16x16x32_bf16(Ah, Bh, aS, 0, 0, 0);
        aS = __builtin_amdgcn_mfma_f32_16x16x32_bf16(Ah, Bl, aS, 0, 0, 0);
        aS = __builtin_amdgcn_mfma_f32_16x16x32_bf16(Al, Bh, aS, 0, 0, 0);
        short8 Ch = kh ? fTh1 : fTh0;
        short8 Cl = kh ? fTl1 : fTl0;
        aY = __builtin_amdgcn_mfma_f32_16x16x32_bf16(Ch, Bh, aY, 0, 0, 0);
        aY = __builtin_amdgcn_mfma_f32_16x16x32_bf16(Ch, Bl, aY, 0, 0, 0);
        aY = __builtin_amdgcn_mfma_f32_16x16x32_bf16(Cl, Bh, aY, 0, 0, 0);
      }
      y[ct] = aY;
      #pragma unroll
      for (int r = 0; r < 4; ++r)
        stT[(wv * 16 + kgrp * 4 + r) * 68 + cc] = aS[r];
    }
    __syncthreads();                                       // B2
    // E fragments: per-iteration (L2-hot after first), overlaps the scan
    short8 fEh0 = LDF(4, 0), fEh1 = LDF(4, 1);
    short8 fEl0 = LDF(5, 0), fEl1 = LDF(5, 1);
    // ---- wave-shuffle scan: lane = chunk, wave wv owns states n = wv*8..wv*8+7 ----
    float ir[8], ii[8];
    {
      float xr[8], xi[8], pr[8], pi[8];
      #pragma unroll
      for (int k = 0; k < 8; ++k) {
        int d0 = wv * 16 + 2 * k;
        xr[k] = stT[d0 * 68 + lane];
        xi[k] = stT[(d0 + 1) * 68 + lane];
        pr[k] = pr0[k];
        pi[k] = pi0[k];
      }
      #pragma unroll
      for (int d = 1; d < 64; d <<= 1) {
        #pragma unroll
        for (int k = 0; k < 8; ++k) {
          float qr = __shfl_up(xr[k], d);
          float qi = __shfl_up(xi[k], d);
          if (lane >= d) {
            xr[k] = fmaf(pr[k], qr, fmaf(-pi[k], qi, xr[k]));
            xi[k] = fmaf(pr[k], qi, fmaf(pi[k], qr, xi[k]));
          }
          float t0 = pr[k] * pr[k] - pi[k] * pi[k];
          pi[k] = 2.f * pr[k] * pi[k];
          pr[k] = t0;
        }
      }
      #pragma unroll
      for (int k = 0; k < 8; ++k) {
        ir[k] = __shfl_up(xr[k], 1);
        ii[k] = __shfl_up(xi[k], 1);
        if (lane == 0) { ir[k] = 0.f; ii[k] = 0.f; }
      }
    }
    __syncthreads();                                       // B3 (stT reads done)
    #pragma unroll
    for (int k = 0; k < 8; ++k) {
      int d0 = wv * 16 + 2 * k;
      unsigned int hp = cvtpk(ir[k], ii[k]);
      float rr = ir[k] - __uint_as_float(hp << 16);
      float ri = ii[k] - __uint_as_float(hp & 0xFFFF0000u);
      unsigned int lp = cvtpk(rr, ri);
      *(unsigned int*)&sh[lane * 68 + d0] = hp;
      *(unsigned int*)&sl[lane * 68 + d0] = lp;
    }
    __syncthreads();                                       // B4
    // ---- Phase B: y += E @ S_init ----
    #pragma unroll
    for (int ct = 0; ct < 4; ++ct) {
      f32x4 a = y[ct];
      int cc = ct * 16 + row16;
      #pragma unroll
      for (int kh = 0; kh < 2; ++kh) {
        int kb = kh * 32 + kgrp * 4;
        short8 Sh8 = ld8(&sh[cc * 68 + kb]);
        short8 Sl8 = ld8(&sl[cc * 68 + kb]);
        short8 Ah = kh ? fEh1 : fEh0;
        short8 Al = kh ? fEl1 : fEl0;
        a = __builtin_amdgcn_mfma_f32_16x16x32_bf16(Ah, Sh8, a, 0, 0, 0);
        a = __builtin_amdgcn_mfma_f32_16x16x32_bf16(Ah, Sl8, a, 0, 0, 0);
        a = __builtin_amdgcn_mfma_f32_16x16x32_bf16(Al, Sh8, a, 0, 0, 0);
      }
      y[ct] = a;
    }
    __syncthreads();                                       // B5
    // ---- epilogue: v = z*D + y, gelu, pack (cvt_pk), uint4 into aliased buffer ----
    {
      int j0 = wv * 16 + kgrp * 4;
      #pragma unroll
      for (int ct = 0; ct < 4; ++ct) {
        int cc = ct * 16 + row16;
        unsigned int za = *(const unsigned int*)&zh[cc * 68 + j0];
        unsigned int zb = *(const unsigned int*)&zh[cc * 68 + j0 + 2];
        unsigned int la = *(const unsigned int*)&zl[cc * 68 + j0];
        unsigned int lb = *(const unsigned int*)&zl[cc * 68 + j0 + 2];
        float zf[4];
        zf[0] = __uint_as_float(za << 16) + __uint_as_float(la << 16);
        zf[1] = __uint_as_float(za & 0xFFFF0000u) + __uint_as_float(la & 0xFFFF0000u);
        zf[2] = __uint_as_float(zb << 16) + __uint_as_float(lb << 16);
        zf[3] = __uint_as_float(zb & 0xFFFF0000u) + __uint_as_float(lb & 0xFFFF0000u);
        float v[4];
        #pragma unroll
        for (int r = 0; r < 4; ++r) {
          float vv = fmaf(zf[r], Dh, y[ct][r]);
          float u = 1.5957691216057308f * fmaf(0.044715f * vv, vv * vv, vv);
          v[r] = vv / (1.f + __expf(-u));
        }
        unsigned int h01 = cvtpk(v[0], v[1]);
        unsigned int h23 = cvtpk(v[2], v[3]);
        float r0 = v[0] - __uint_as_float(h01 << 16);
        float r1 = v[1] - __uint_as_float(h01 & 0xFFFF0000u);
        float r2 = v[2] - __uint_as_float(h23 << 16);
        float r3 = v[3] - __uint_as_float(h23 & 0xFFFF0000u);
        unsigned int l01 = cvtpk(r0, r1);
        unsigned int l23 = cvtpk(r2, r3);
        uint4 w;
        w.x = (h01 << 16) | (l01 & 0xFFFFu);
        w.y = (h01 & 0xFFFF0000u) | (l01 >> 16);
        w.z = (h23 << 16) | (l23 & 0xFFFFu);
        w.w = (h23 & 0xFFFF0000u) | (l23 >> 16);
        *(uint4*)&packbuf[cc * 68 + j0] = w;
      }
    }
    __syncthreads();                                       // B6
    {
      unsigned int* grow = gout + bh * LL;
      #pragma unroll
      for (int q = 0; q < 4; ++q) {
        uint4 v = *(const uint4*)&packbuf[c0 * 68 + i0 + q * 4];
        *(uint4*)&grow[c0 * 64 + i0 + q * 4] = v;
      }
    }
  }
  #undef LDF
}

// ---------------- MFMA matmul + bias + residual + LayerNorm (fragment-major W) ----------------
// R10 verbatim. template<LAST>: last layer fuses the decoder (reads normalized tile from LDS).
template<int LAST>
__global__ __launch_bounds__(256, 4) void mm_mfma_ln_kernel(
    const unsigned int* __restrict__ gp, float* __restrict__ h_buf,
    const unsigned int* __restrict__ Wp, const float* __restrict__ bo,
    const float* __restrict__ lw, const float* __restrict__ lb,
    const float* __restrict__ dcw, const float* __restrict__ dcb,
    float* __restrict__ outp) {
  __shared__ float smem[HH * 33];            // gt (first 32KB); LAST also uses as rt
  __shared__ float red_s[4][BN];
  __shared__ float red_q[4][BN];
  unsigned int* gt = (unsigned int*)smem;
  float* rt = smem;
  int blk = blockIdx.x;
  int b = blk >> 7;
  int l0 = (blk & 127) * BN;
  int t = threadIdx.x;
  const unsigned int* gbase = gp + (size_t)b * HH * LL + l0;
  #pragma unroll
  for (int p = 0; p < 4; ++p) {
    int hh = p * 64 + (t >> 2);
    int lq = (t & 3) * 8;
    const uint4* src = (const uint4*)(gbase + (size_t)hh * LL + lq);
    uint4 v0 = src[0];
    uint4 v1 = src[1];
    unsigned int vals[8] = {v0.x, v0.y, v0.z, v0.w, v1.x, v1.y, v1.z, v1.w};
    #pragma unroll
    for (int j = 0; j < 8; ++j) {
      int l = lq + j;
      int xm = (l & 7) ^ ((l >> 3) & 3);
      int g4 = (hh >> 2) ^ xm;
      gt[l * HH + g4 * 4 + (hh & 3)] = vals[j];
    }
  }
  __syncthreads();
  int wv = t >> 6, lane = t & 63;
  int row16 = lane & 15, kgrp = lane >> 4;
  f32x4 acc[4][2];
  #pragma unroll
  for (int di = 0; di < 4; ++di)
    #pragma unroll
    for (int li = 0; li < 2; ++li)
      acc[di][li] = (f32x4){0.f, 0.f, 0.f, 0.f};
  #pragma unroll 2
  for (int ks = 0; ks < 8; ++ks) {
    int h0 = ks * 32;
    short8 Bhi[2], Blo[2];
    #pragma unroll
    for (int li = 0; li < 2; ++li) {
      int l = li * 16 + row16;
      int xm = (l & 7) ^ ((l >> 3) & 3);
      int g4a = ((h0 >> 2) + kgrp) ^ xm;
      int g4b = ((h0 >> 2) + kgrp + 4) ^ xm;
      uint4 pa = *(const uint4*)&gt[l * HH + g4a * 4];
      uint4 pb = *(const uint4*)&gt[l * HH + g4b * 4];
      union { int i[4]; short8 s; } uh, ul;
      uh.i[0] = (int)((pa.x >> 16) | (pa.y & 0xFFFF0000u));
      uh.i[1] = (int)((pa.z >> 16) | (pa.w & 0xFFFF0000u));
      uh.i[2] = (int)((pb.x >> 16) | (pb.y & 0xFFFF0000u));
      uh.i[3] = (int)((pb.z >> 16) | (pb.w & 0xFFFF0000u));
      ul.i[0] = (int)((pa.x & 0xFFFFu) | (pa.y << 16));
      ul.i[1] = (int)((pa.z & 0xFFFFu) | (pa.w << 16));
      ul.i[2] = (int)((pb.x & 0xFFFFu) | (pb.y << 16));
      ul.i[3] = (int)((pb.z & 0xFFFFu) | (pb.w << 16));
      Bhi[li] = uh.s; Blo[li] = ul.s;
    }
    #pragma unroll
    for (int di = 0; di < 4; ++di) {
      const uint4* wf = (const uint4*)Wp + ((((wv * 8 + ks) * 4 + di) * 64 + lane) * 2);
      uint4 pa = wf[0];
      uint4 pb = wf[1];
      union { int i[4]; short8 s; } uh, ul;
      uh.i[0] = (int)((pa.x >> 16) | (pa.y & 0xFFFF0000u));
      uh.i[1] = (int)((pa.z >> 16) | (pa.w & 0xFFFF0000u));
      uh.i[2] = (int)((pb.x >> 16) | (pb.y & 0xFFFF0000u));
      uh.i[3] = (int)((pb.z >> 16) | (pb.w & 0xFFFF0000u));
      ul.i[0] = (int)((pa.x & 0xFFFFu) | (pa.y << 16));
      ul.i[1] = (int)((pa.z & 0xFFFFu) | (pa.w << 16));
      ul.i[2] = (int)((pb.x & 0xFFFFu) | (pb.y << 16));
      ul.i[3] = (int)((pb.z & 0xFFFFu) | (pb.w << 16));
      short8 Ahi = uh.s, Alo = ul.s;
      #pragma unroll
      for (int li = 0; li < 2; ++li) {
        acc[di][li] = __builtin_amdgcn_mfma_f32_16x16x32_bf16(Ahi, Bhi[li], acc[di][li], 0, 0, 0);
        acc[di][li] = __builtin_amdgcn_mfma_f32_16x16x32_bf16(Ahi, Blo[li], acc[di][li], 0, 0, 0);
        acc[di][li] = __builtin_amdgcn_mfma_f32_16x16x32_bf16(Alo, Bhi[li], acc[di][li], 0, 0, 0);
      }
    }
  }
  const float* hb = h_buf + (size_t)b * HH * LL + l0;
  #pragma unroll
  for (int di = 0; di < 4; ++di) {
    #pragma unroll
    for (int r = 0; r < 4; ++r) {
      int d = wv * 64 + di * 16 + kgrp * 4 + r;
      float bov = bo[d];
      #pragma unroll
      for (int li = 0; li < 2; ++li) {
        int l = li * 16 + row16;
        acc[di][li][r] += bov + hb[(size_t)d * LL + l];
      }
    }
  }
  #pragma unroll
  for (int li = 0; li < 2; ++li) {
    float s = 0.f, q = 0.f;
    #pragma unroll
    for (int di = 0; di < 4; ++di)
      #pragma unroll
      for (int r = 0; r < 4; ++r) {
        float v = acc[di][li][r];
        s += v;
        q = fmaf(v, v, q);
      }
    s += __shfl_xor(s, 16); s += __shfl_xor(s, 32);
    q += __shfl_xor(q, 16); q += __shfl_xor(q, 32);
    if (lane < 16) {
      red_s[wv][li * 16 + lane] = s;
      red_q[wv][li * 16 + lane] = q;
    }
  }
  __syncthreads();   // red visible; also all gt reads complete (K-loop is before)
  float mu[2], rstd[2];
  #pragma unroll
  for (int li = 0; li < 2; ++li) {
    int cl = li * 16 + row16;
    float s = red_s[0][cl] + red_s[1][cl] + red_s[2][cl] + red_s[3][cl];
    float q = red_q[0][cl] + red_q[1][cl] + red_q[2][cl] + red_q[3][cl];
    float m = s * (1.f / 256.f);
    float var = q * (1.f / 256.f) - m * m;
    mu[li] = m;
    rstd[li] = rsqrtf(var + 1e-5f);
  }
  if (!LAST) {
    float* hw = h_buf + (size_t)b * HH * LL + l0;
    #pragma unroll
    for (int di = 0; di < 4; ++di) {
      #pragma unroll
      for (int r = 0; r < 4; ++r) {
        int d = wv * 64 + di * 16 + kgrp * 4 + r;
        float lwv = lw[d], lbv = lb[d];
        #pragma unroll
        for (int li = 0; li < 2; ++li) {
          int l = li * 16 + row16;
          hw[(size_t)d * LL + l] = (acc[di][li][r] - mu[li]) * rstd[li] * lwv + lbv;
        }
      }
    }
  } else {
    // route normalized tile through LDS (gt dead), then fused decoder
    #pragma unroll
    for (int di = 0; di < 4; ++di) {
      #pragma unroll
      for (int r = 0; r < 4; ++r) {
        int d = wv * 64 + di * 16 + kgrp * 4 + r;
        float lwv = lw[d], lbv = lb[d];
        #pragma unroll
        for (int li = 0; li < 2; ++li) {
          int l = li * 16 + row16;
          rt[d * 33 + l] = (acc[di][li][r] - mu[li]) * rstd[li] * lwv + lbv;
        }
      }
    }
    __syncthreads();
    int l = t & 31, dd = t >> 5;   // dd 0..7; thread covers dd and dd+8
    float a0 = dcb[dd], a1 = dcb[dd + 8];
    #pragma unroll 8
    for (int d = 0; d < HH; ++d) {
      float hv = rt[d * 33 + l];
      a0 = fmaf(hv, dcw[d * DIN + dd], a0);
      a1 = fmaf(hv, dcw[d * DIN + dd + 8], a1);
    }
    float* ob = outp + (size_t)b * DIN * LL + l0;
    ob[(size_t)dd * LL + l] = a0;
    ob[(size_t)(dd + 8) * LL + l] = a1;
  }
}

extern "C" void kernel_launch(void* const* d_in, const int* in_sizes, int n_in,
                              void* d_out, int out_size, void* d_ws, size_t ws_size,
                              hipStream_t stream) {
  const float* x      = (const float*)d_in[0];
  const float* enc_w  = (const float*)d_in[1];
  const float* enc_b  = (const float*)d_in[2];
  const float* log_dt = (const float*)d_in[3];
  const float* A_re   = (const float*)d_in[4];
  const float* A_im   = (const float*)d_in[5];
  const float* C_re   = (const float*)d_in[6];
  const float* C_im   = (const float*)d_in[7];
  const float* Dv     = (const float*)d_in[8];
  const float* W_out  = (const float*)d_in[9];
  const float* b_out  = (const float*)d_in[10];
  const float* ln_w   = (const float*)d_in[11];
  const float* ln_b   = (const float*)d_in[12];
  const float* dec_w  = (const float*)d_in[13];
  const float* dec_b  = (const float*)d_in[14];
  float* out = (float*)d_out;

  float* h_buf = (float*)d_ws;
  unsigned int* g_pack = (unsigned int*)(h_buf + (size_t)Bb * HH * LL);
  float* w64 = (float*)(g_pack + (size_t)Bb * HH * LL);
  unsigned int* Wp = (unsigned int*)(w64 + 2 * HN);
  u16* Bf = (u16*)(Wp + HH * HH);

  enc_kernel<<<Bb * HH * (LL / 256), 256, 0, stream>>>(x, enc_w, enc_b, h_buf);
  for (int i = 0; i < NLAY; ++i) {
    prep_kernel<<<2 * HH, 256, 0, stream>>>(log_dt + i * HH, A_re + i * HN,
                                            A_im + i * HN, C_re + i * HN,
                                            C_im + i * HN, w64, Bf,
                                            W_out + (size_t)i * HH * HH, Wp);
    s4_mfma_kernel<<<4 * HH, 256, 0, stream>>>(h_buf, w64, Dv + i * HH, Bf, g_pack);
    if (i < NLAY - 1) {
      mm_mfma_ln_kernel<0><<<Bb * (LL / BN), 256, 0, stream>>>(
          g_pack, h_buf, Wp, b_out + i * HH, ln_w + i * HH, ln_b + i * HH,
          dec_w, dec_b, out);
    } else {
      mm_mfma_ln_kernel<1><<<Bb * (LL / BN), 256, 0, stream>>>(
          g_pack, h_buf, Wp, b_out + i * HH, ln_w + i * HH, ln_b + i * HH,
          dec_w, dec_b, out);
    }
  }
}

// Round 14
// 655.030 us; speedup vs baseline: 1.3613x; 1.3613x over previous
//
#include <hip/hip_runtime.h>
#include <hip/hip_bf16.h>
#include <math.h>

#define Bb 16
#define DIN 16
#define LL 4096
#define HH 256
#define NN2 32
#define NLAY 4
#define HN (HH*NN2)
#define BN 32          // mm l-tile

typedef __attribute__((ext_vector_type(8))) short short8;
typedef __attribute__((ext_vector_type(4))) short short4v;
typedef __attribute__((ext_vector_type(4))) float f32x4;
typedef unsigned short u16;

__device__ inline u16 f2bf(float f) {
  unsigned int x = __float_as_uint(f);
  unsigned int r = x + 0x7FFFu + ((x >> 16) & 1u);   // RNE
  return (u16)(r >> 16);
}
__device__ inline float bf2f(u16 u) {
  return __uint_as_float(((unsigned int)u) << 16);
}
__device__ inline unsigned int packsplit(float v) {
  u16 hi = f2bf(v);
  u16 lo = f2bf(v - bf2f(hi));
  return (((unsigned int)hi) << 16) | lo;
}
// v_cvt_pk_bf16_f32: low16 = bf16(a), high16 = bf16(b), RNE
__device__ inline unsigned int cvtpk(float a, float b) {
  unsigned int r;
  asm("v_cvt_pk_bf16_f32 %0, %1, %2" : "=v"(r) : "v"(a), "v"(b));
  return r;
}
// LDS fragment loader: 4 u16 at p, 4 u16 at p+16 (k and k+16 halves)
__device__ inline short8 ld8(const u16* p) {
  short4v a = *(const short4v*)p;
  short4v b = *(const short4v*)(p + 16);
  return __builtin_shufflevector(a, b, 0, 1, 2, 3, 4, 5, 6, 7);
}
// fragment-major index for basis matrices: m in 0..5 (Th,Tl,Mh,Ml,Eh,El)
__device__ inline size_t fidx(int h, int m, int row, int col) {
  int wv = row >> 4, row16 = row & 15;
  int kh = col >> 5, c5 = col & 31;
  int lane = ((c5 & 15) >> 2) * 16 + row16;
  int j = (((c5 >> 4) & 1) << 2) | (c5 & 3);
  return ((((((size_t)h * 6 + m) * 4 + wv) * 2 + kh) * 64 + lane) << 3) + j;
}

// ---------------- encoder ----------------
__global__ __launch_bounds__(256) void enc_kernel(const float* __restrict__ x,
    const float* __restrict__ ew, const float* __restrict__ eb,
    float* __restrict__ hbuf) {
  int blk = blockIdx.x;
  int tile = blk & 15;
  int h = (blk >> 4) & (HH - 1);
  int b = blk >> 12;
  int l = tile * 256 + threadIdx.x;
  const float* xb = x + (size_t)b * DIN * LL + l;
  float acc = eb[h];
  #pragma unroll
  for (int i = 0; i < DIN; ++i)
    acc = fmaf(xb[(size_t)i * LL], ew[i * HH + h], acc);
  hbuf[((size_t)(b * HH + h)) * LL + l] = acc;
}

// ---------------- basis (coef fused): T/M/E in fragment-major layout + w64 ----------------
__global__ __launch_bounds__(256) void basis_kernel(
    const float* __restrict__ log_dt, const float* __restrict__ Are,
    const float* __restrict__ Aim, const float* __restrict__ Cre,
    const float* __restrict__ Cim, float* __restrict__ w64,
    u16* __restrict__ Bf) {
  __shared__ float K_l[64];
  int h = blockIdx.x;
  int t = threadIdx.x;
  if (t < 32) {
    int n = t;
    int idx = h * 32 + n;
    float dt = expf(log_dt[h]);
    float ar = -expf(Are[idx]);
    float ai = Aim[idx];
    float er = expf(ar * dt);
    float wr = er * cosf(ai * dt);
    float wi = er * sinf(ai * dt);
    float nr = wr - 1.f, ni = wi;
    float inv = 1.f / (ar * ar + ai * ai);
    float qr = (nr * ar + ni * ai) * inv;
    float qi = (ni * ar - nr * ai) * inv;
    float crv = Cre[idx], civ = Cim[idx];
    float cr = 2.f * (crv * qr - civ * qi);
    float ci = 2.f * (crv * qi + civ * qr);
    // w^64 for the scan
    float pr = wr, pi = wi;
    #pragma unroll
    for (int q = 0; q < 6; ++q) {
      float t0 = pr * pr - pi * pi;
      pi = 2.f * pr * pi;
      pr = t0;
    }
    w64[idx] = pr;
    w64[HN + idx] = pi;
    // M, E, K
    float vr = 1.f, vi = 0.f;
    for (int m = 0; m <= 64; ++m) {
      float e = cr * vr - ci * vi;
      float f = -(cr * vi + ci * vr);
      float s = e;
      s += __shfl_xor(s, 1); s += __shfl_xor(s, 2); s += __shfl_xor(s, 4);
      s += __shfl_xor(s, 8); s += __shfl_xor(s, 16);
      if (m <= 63) {
        if (n == 0) K_l[m] = s;
        int i = 63 - m;
        u16 hr = f2bf(vr);
        Bf[fidx(h, 2, 2 * n, i)] = hr;
        Bf[fidx(h, 3, 2 * n, i)] = f2bf(vr - bf2f(hr));
        u16 hi2 = f2bf(vi);
        Bf[fidx(h, 2, 2 * n + 1, i)] = hi2;
        Bf[fidx(h, 3, 2 * n + 1, i)] = f2bf(vi - bf2f(hi2));
      }
      if (m >= 1) {
        int row = m - 1;
        u16 he = f2bf(e);
        Bf[fidx(h, 4, row, 2 * n)] = he;
        Bf[fidx(h, 5, row, 2 * n)] = f2bf(e - bf2f(he));
        u16 hf = f2bf(f);
        Bf[fidx(h, 4, row, 2 * n + 1)] = hf;
        Bf[fidx(h, 5, row, 2 * n + 1)] = f2bf(f - bf2f(hf));
      }
      float nvr = vr * wr - vi * wi;
      float nvi = vr * wi + vi * wr;
      vr = nvr; vi = nvi;
    }
  }
  __syncthreads();
  #pragma unroll
  for (int p = 0; p < 16; ++p) {
    int id = p * 256 + t;
    int j = id >> 6, i = id & 63;
    float kv = (j >= i) ? K_l[j - i] : 0.f;
    u16 hi = f2bf(kv);
    Bf[fidx(h, 0, j, i)] = hi;
    Bf[fidx(h, 1, j, i)] = f2bf(kv - bf2f(hi));
  }
}

// ---------------- W pack: fragment-major Wp[wv][ks][di][lane][8] ----------------
__global__ __launch_bounds__(256) void wpack_kernel(const float* __restrict__ W,
                                                    unsigned int* __restrict__ Wp) {
  int idx = blockIdx.x * 256 + threadIdx.x;   // 65536 total
  int j = idx & 7;
  int lane = (idx >> 3) & 63;
  int di = (idx >> 9) & 3;
  int ks = (idx >> 11) & 7;
  int wv = idx >> 14;
  int row16 = lane & 15, kgrp = lane >> 4;
  int d = wv * 64 + di * 16 + row16;
  int hcol = ks * 32 + kgrp * 4 + (j & 3) + ((j >> 2) << 4);
  Wp[idx] = packsplit(W[hcol * HH + d]);
}

// ---------------- MFMA SSM v3: reg-hoisted fragments, cvt_pk conversions (R10 verbatim) ----------------
__global__ __launch_bounds__(256, 4) void s4_mfma_kernel(
    const float* __restrict__ zg, const float* __restrict__ w64,
    const float* __restrict__ Dvec, const u16* __restrict__ Bf,
    unsigned int* __restrict__ gout) {
  __shared__ u16 zh[64 * 68], zl[64 * 68];   // z planes [chunk][i], pad 68
  __shared__ float stT[64 * 68];             // Phase-A ends transposed; aliased later
  u16* sh = (u16*)stT;
  u16* sl = sh + 64 * 68;
  unsigned int* packbuf = (unsigned int*)stT;
  int bh = blockIdx.x, h = bh & (HH - 1), t = threadIdx.x;
  int wv = t >> 6, lane = t & 63, row16 = lane & 15, kgrp = lane >> 4;
  // hoisted A-fragment loads (coalesced 16B each), issued before staging
  const u16* BfH = Bf + (size_t)h * (6 * 4 * 2 * 64 * 8);
  #define LDF(m, kh) (*(const short8*)(BfH + (((m) * 4 + wv) * 2 + (kh)) * 512 + lane * 8))
  short8 fTh0 = LDF(0, 0), fTh1 = LDF(0, 1);
  short8 fTl0 = LDF(1, 0), fTl1 = LDF(1, 1);
  short8 fMh0 = LDF(2, 0), fMh1 = LDF(2, 1);
  short8 fMl0 = LDF(3, 0), fMl1 = LDF(3, 1);
  const float* zrow = zg + (size_t)bh * LL;
  int c0 = t >> 2, i0 = (t & 3) * 16;
  {
    const float4* zsrc = (const float4*)(zrow + c0 * 64 + i0);
    #pragma unroll
    for (int q = 0; q < 4; ++q) {
      float4 v = zsrc[q];
      unsigned int hp0 = cvtpk(v.x, v.y);
      unsigned int hp1 = cvtpk(v.z, v.w);
      float r0 = v.x - __uint_as_float(hp0 << 16);
      float r1 = v.y - __uint_as_float(hp0 & 0xFFFF0000u);
      float r2 = v.z - __uint_as_float(hp1 << 16);
      float r3 = v.w - __uint_as_float(hp1 & 0xFFFF0000u);
      unsigned int lp0 = cvtpk(r0, r1);
      unsigned int lp1 = cvtpk(r2, r3);
      int base = c0 * 68 + i0 + q * 4;
      *(unsigned int*)&zh[base] = hp0;
      *(unsigned int*)&zh[base + 2] = hp1;
      *(unsigned int*)&zl[base] = lp0;
      *(unsigned int*)&zl[base + 2] = lp1;
    }
  }
  __syncthreads();                                         // B1
  f32x4 y[4];
  // ---- Phase A: S_end = M@Z (stT transposed) and y = T@Z, shared z frags ----
  #pragma unroll
  for (int ct = 0; ct < 4; ++ct) {
    f32x4 aS = (f32x4){0.f, 0.f, 0.f, 0.f};
    f32x4 aY = (f32x4){0.f, 0.f, 0.f, 0.f};
    int cc = ct * 16 + row16;
    #pragma unroll
    for (int kh = 0; kh < 2; ++kh) {
      int kb = kh * 32 + kgrp * 4;
      short8 Bh = ld8(&zh[cc * 68 + kb]);
      short8 Bl = ld8(&zl[cc * 68 + kb]);
      short8 Ah = kh ? fMh1 : fMh0;
      short8 Al = kh ? fMl1 : fMl0;
      aS = __builtin_amdgcn_mfma_f32_16x16x32_bf16(Ah, Bh, aS, 0, 0, 0);
      aS = __builtin_amdgcn_mfma_f32_16x16x32_bf16(Ah, Bl, aS, 0, 0, 0);
      aS = __builtin_amdgcn_mfma_f32_16x16x32_bf16(Al, Bh, aS, 0, 0, 0);
      short8 Ch = kh ? fTh1 : fTh0;
      short8 Cl = kh ? fTl1 : fTl0;
      aY = __builtin_amdgcn_mfma_f32_16x16x32_bf16(Ch, Bh, aY, 0, 0, 0);
      aY = __builtin_amdgcn_mfma_f32_16x16x32_bf16(Ch, Bl, aY, 0, 0, 0);
      aY = __builtin_amdgcn_mfma_f32_16x16x32_bf16(Cl, Bh, aY, 0, 0, 0);
    }
    y[ct] = aY;
    #pragma unroll
    for (int r = 0; r < 4; ++r)
      stT[(wv * 16 + kgrp * 4 + r) * 68 + cc] = aS[r];
  }
  __syncthreads();                                         // B2
  // E fragments: load now so latency overlaps the scan
  short8 fEh0 = LDF(4, 0), fEh1 = LDF(4, 1);
  short8 fEl0 = LDF(5, 0), fEl1 = LDF(5, 1);
  #undef LDF
  // ---- wave-shuffle scan: lane = chunk, wave wv owns states n = wv*8..wv*8+7 ----
  float ir[8], ii[8];
  {
    float xr[8], xi[8], pr[8], pi[8];
    #pragma unroll
    for (int k = 0; k < 8; ++k) {
      int d0 = wv * 16 + 2 * k;
      xr[k] = stT[d0 * 68 + lane];
      xi[k] = stT[(d0 + 1) * 68 + lane];
      pr[k] = w64[h * 32 + wv * 8 + k];
      pi[k] = w64[HN + h * 32 + wv * 8 + k];
    }
    #pragma unroll
    for (int d = 1; d < 64; d <<= 1) {
      #pragma unroll
      for (int k = 0; k < 8; ++k) {
        float qr = __shfl_up(xr[k], d);
        float qi = __shfl_up(xi[k], d);
        if (lane >= d) {
          xr[k] = fmaf(pr[k], qr, fmaf(-pi[k], qi, xr[k]));
          xi[k] = fmaf(pr[k], qi, fmaf(pi[k], qr, xi[k]));
        }
        float t0 = pr[k] * pr[k] - pi[k] * pi[k];
        pi[k] = 2.f * pr[k] * pi[k];
        pr[k] = t0;
      }
    }
    #pragma unroll
    for (int k = 0; k < 8; ++k) {
      ir[k] = __shfl_up(xr[k], 1);
      ii[k] = __shfl_up(xi[k], 1);
      if (lane == 0) { ir[k] = 0.f; ii[k] = 0.f; }
    }
  }
  __syncthreads();                                         // B3 (stT reads done)
  #pragma unroll
  for (int k = 0; k < 8; ++k) {
    int d0 = wv * 16 + 2 * k;
    unsigned int hp = cvtpk(ir[k], ii[k]);
    float rr = ir[k] - __uint_as_float(hp << 16);
    float ri = ii[k] - __uint_as_float(hp & 0xFFFF0000u);
    unsigned int lp = cvtpk(rr, ri);
    *(unsigned int*)&sh[lane * 68 + d0] = hp;
    *(unsigned int*)&sl[lane * 68 + d0] = lp;
  }
  __syncthreads();                                         // B4
  // ---- Phase B: y += E @ S_init ----
  #pragma unroll
  for (int ct = 0; ct < 4; ++ct) {
    f32x4 a = y[ct];
    int cc = ct * 16 + row16;
    #pragma unroll
    for (int kh = 0; kh < 2; ++kh) {
      int kb = kh * 32 + kgrp * 4;
      short8 Sh8 = ld8(&sh[cc * 68 + kb]);
      short8 Sl8 = ld8(&sl[cc * 68 + kb]);
      short8 Ah = kh ? fEh1 : fEh0;
      short8 Al = kh ? fEl1 : fEl0;
      a = __builtin_amdgcn_mfma_f32_16x16x32_bf16(Ah, Sh8, a, 0, 0, 0);
      a = __builtin_amdgcn_mfma_f32_16x16x32_bf16(Ah, Sl8, a, 0, 0, 0);
      a = __builtin_amdgcn_mfma_f32_16x16x32_bf16(Al, Sh8, a, 0, 0, 0);
    }
    y[ct] = a;
  }
  __syncthreads();                                         // B5
  // ---- epilogue: v = z*D + y, gelu, pack (cvt_pk), uint4 into aliased buffer ----
  {
    float Dh = Dvec[h];
    int j0 = wv * 16 + kgrp * 4;
    #pragma unroll
    for (int ct = 0; ct < 4; ++ct) {
      int cc = ct * 16 + row16;
      unsigned int za = *(const unsigned int*)&zh[cc * 68 + j0];
      unsigned int zb = *(const unsigned int*)&zh[cc * 68 + j0 + 2];
      unsigned int la = *(const unsigned int*)&zl[cc * 68 + j0];
      unsigned int lb = *(const unsigned int*)&zl[cc * 68 + j0 + 2];
      float zf[4];
      zf[0] = __uint_as_float(za << 16) + __uint_as_float(la << 16);
      zf[1] = __uint_as_float(za & 0xFFFF0000u) + __uint_as_float(la & 0xFFFF0000u);
      zf[2] = __uint_as_float(zb << 16) + __uint_as_float(lb << 16);
      zf[3] = __uint_as_float(zb & 0xFFFF0000u) + __uint_as_float(lb & 0xFFFF0000u);
      float v[4];
      #pragma unroll
      for (int r = 0; r < 4; ++r) {
        float vv = fmaf(zf[r], Dh, y[ct][r]);
        float u = 1.5957691216057308f * fmaf(0.044715f * vv, vv * vv, vv);
        v[r] = vv / (1.f + __expf(-u));
      }
      unsigned int h01 = cvtpk(v[0], v[1]);
      unsigned int h23 = cvtpk(v[2], v[3]);
      float r0 = v[0] - __uint_as_float(h01 << 16);
      float r1 = v[1] - __uint_as_float(h01 & 0xFFFF0000u);
      float r2 = v[2] - __uint_as_float(h23 << 16);
      float r3 = v[3] - __uint_as_float(h23 & 0xFFFF0000u);
      unsigned int l01 = cvtpk(r0, r1);
      unsigned int l23 = cvtpk(r2, r3);
      uint4 w;
      w.x = (h01 << 16) | (l01 & 0xFFFFu);
      w.y = (h01 & 0xFFFF0000u) | (l01 >> 16);
      w.z = (h23 << 16) | (l23 & 0xFFFFu);
      w.w = (h23 & 0xFFFF0000u) | (l23 >> 16);
      *(uint4*)&packbuf[cc * 68 + j0] = w;
    }
  }
  __syncthreads();                                         // B6
  {
    unsigned int* grow = gout + (size_t)bh * LL;
    #pragma unroll
    for (int q = 0; q < 4; ++q) {
      uint4 v = *(const uint4*)&packbuf[c0 * 68 + i0 + q * 4];
      *(uint4*)&grow[c0 * 64 + i0 + q * 4] = v;
    }
  }
}

// ---------------- MFMA matmul + bias + residual + LayerNorm ----------------
// R10 K-loop verbatim; residual path from R8 (proven 70-71 us): float4 res prefetch
// before staging, residual routed through LDS aliased over dead g-tile, LN in place,
// coalesced float4 row stores. template<LAST>: fused decoder reads normalized tile.
template<int LAST>
__global__ __launch_bounds__(256, 4) void mm_mfma_ln_kernel(
    const unsigned int* __restrict__ gp, float* __restrict__ h_buf,
    const unsigned int* __restrict__ Wp, const float* __restrict__ bo,
    const float* __restrict__ lw, const float* __restrict__ lb,
    const float* __restrict__ dcw, const float* __restrict__ dcb,
    float* __restrict__ outp) {
  __shared__ float smem[HH * 33];            // gt (first 32KB); then rt (aliased)
  __shared__ float red_s[4][BN];
  __shared__ float red_q[4][BN];
  unsigned int* gt = (unsigned int*)smem;
  float* rt = smem;                          // [256][33]
  int blk = blockIdx.x;
  int b = blk >> 7;
  int l0 = (blk & 127) * BN;
  int t = threadIdx.x;
  const unsigned int* gbase = gp + (size_t)b * HH * LL + l0;
  const float* hbp = h_buf + (size_t)b * HH * LL + l0;
  // residual prefetch: fully-coalesced 128B rows into registers (hides L3 latency)
  float4 res[8];
  #pragma unroll
  for (int p = 0; p < 8; ++p) {
    int row = p * 32 + (t >> 3);
    int c4 = (t & 7) * 4;
    res[p] = *(const float4*)(hbp + (size_t)row * LL + c4);
  }
  #pragma unroll
  for (int p = 0; p < 4; ++p) {
    int hh = p * 64 + (t >> 2);
    int lq = (t & 3) * 8;
    const uint4* src = (const uint4*)(gbase + (size_t)hh * LL + lq);
    uint4 v0 = src[0];
    uint4 v1 = src[1];
    unsigned int vals[8] = {v0.x, v0.y, v0.z, v0.w, v1.x, v1.y, v1.z, v1.w};
    #pragma unroll
    for (int j = 0; j < 8; ++j) {
      int l = lq + j;
      int xm = (l & 7) ^ ((l >> 3) & 3);
      int g4 = (hh >> 2) ^ xm;
      gt[l * HH + g4 * 4 + (hh & 3)] = vals[j];
    }
  }
  __syncthreads();                           // B1: gt staged
  int wv = t >> 6, lane = t & 63;
  int row16 = lane & 15, kgrp = lane >> 4;
  f32x4 acc[4][2];
  #pragma unroll
  for (int di = 0; di < 4; ++di)
    #pragma unroll
    for (int li = 0; li < 2; ++li)
      acc[di][li] = (f32x4){0.f, 0.f, 0.f, 0.f};
  #pragma unroll 2
  for (int ks = 0; ks < 8; ++ks) {
    int h0 = ks * 32;
    short8 Bhi[2], Blo[2];
    #pragma unroll
    for (int li = 0; li < 2; ++li) {
      int l = li * 16 + row16;
      int xm = (l & 7) ^ ((l >> 3) & 3);
      int g4a = ((h0 >> 2) + kgrp) ^ xm;
      int g4b = ((h0 >> 2) + kgrp + 4) ^ xm;
      uint4 pa = *(const uint4*)&gt[l * HH + g4a * 4];
      uint4 pb = *(const uint4*)&gt[l * HH + g4b * 4];
      union { int i[4]; short8 s; } uh, ul;
      uh.i[0] = (int)((pa.x >> 16) | (pa.y & 0xFFFF0000u));
      uh.i[1] = (int)((pa.z >> 16) | (pa.w & 0xFFFF0000u));
      uh.i[2] = (int)((pb.x >> 16) | (pb.y & 0xFFFF0000u));
      uh.i[3] = (int)((pb.z >> 16) | (pb.w & 0xFFFF0000u));
      ul.i[0] = (int)((pa.x & 0xFFFFu) | (pa.y << 16));
      ul.i[1] = (int)((pa.z & 0xFFFFu) | (pa.w << 16));
      ul.i[2] = (int)((pb.x & 0xFFFFu) | (pb.y << 16));
      ul.i[3] = (int)((pb.z & 0xFFFFu) | (pb.w << 16));
      Bhi[li] = uh.s; Blo[li] = ul.s;
    }
    #pragma unroll
    for (int di = 0; di < 4; ++di) {
      const uint4* wf = (const uint4*)Wp + ((((wv * 8 + ks) * 4 + di) * 64 + lane) * 2);
      uint4 pa = wf[0];
      uint4 pb = wf[1];
      union { int i[4]; short8 s; } uh, ul;
      uh.i[0] = (int)((pa.x >> 16) | (pa.y & 0xFFFF0000u));
      uh.i[1] = (int)((pa.z >> 16) | (pa.w & 0xFFFF0000u));
      uh.i[2] = (int)((pb.x >> 16) | (pb.y & 0xFFFF0000u));
      uh.i[3] = (int)((pb.z >> 16) | (pb.w & 0xFFFF0000u));
      ul.i[0] = (int)((pa.x & 0xFFFFu) | (pa.y << 16));
      ul.i[1] = (int)((pa.z & 0xFFFFu) | (pa.w << 16));
      ul.i[2] = (int)((pb.x & 0xFFFFu) | (pb.y << 16));
      ul.i[3] = (int)((pb.z & 0xFFFFu) | (pb.w << 16));
      short8 Ahi = uh.s, Alo = ul.s;
      #pragma unroll
      for (int li = 0; li < 2; ++li) {
        acc[di][li] = __builtin_amdgcn_mfma_f32_16x16x32_bf16(Ahi, Bhi[li], acc[di][li], 0, 0, 0);
        acc[di][li] = __builtin_amdgcn_mfma_f32_16x16x32_bf16(Ahi, Blo[li], acc[di][li], 0, 0, 0);
        acc[di][li] = __builtin_amdgcn_mfma_f32_16x16x32_bf16(Alo, Bhi[li], acc[di][li], 0, 0, 0);
      }
    }
  }
  __syncthreads();                           // B2: gt dead -> reuse smem as residual tile
  #pragma unroll
  for (int p = 0; p < 8; ++p) {
    int row = p * 32 + (t >> 3);
    int c4 = (t & 7) * 4;
    float* dst = &rt[row * 33 + c4];
    dst[0] = res[p].x; dst[1] = res[p].y; dst[2] = res[p].z; dst[3] = res[p].w;
  }
  __syncthreads();                           // B3: rt (residual) visible
  float vv[4][2][4];
  #pragma unroll
  for (int di = 0; di < 4; ++di) {
    #pragma unroll
    for (int r = 0; r < 4; ++r) {
      int d = wv * 64 + di * 16 + kgrp * 4 + r;
      float bov = bo[d];
      #pragma unroll
      for (int li = 0; li < 2; ++li) {
        int l = li * 16 + row16;
        vv[di][li][r] = acc[di][li][r] + bov + rt[d * 33 + l];
      }
    }
  }
  #pragma unroll
  for (int li = 0; li < 2; ++li) {
    float s = 0.f, q = 0.f;
    #pragma unroll
    for (int di = 0; di < 4; ++di)
      #pragma unroll
      for (int r = 0; r < 4; ++r) {
        float v = vv[di][li][r];
        s += v;
        q = fmaf(v, v, q);
      }
    s += __shfl_xor(s, 16); s += __shfl_xor(s, 32);
    q += __shfl_xor(q, 16); q += __shfl_xor(q, 32);
    if (lane < 16) {
      red_s[wv][li * 16 + lane] = s;
      red_q[wv][li * 16 + lane] = q;
    }
  }
  __syncthreads();                           // B4: red visible (all rt residual reads done)
  float mu[2], rstd[2];
  #pragma unroll
  for (int li = 0; li < 2; ++li) {
    int cl = li * 16 + row16;
    float s = red_s[0][cl] + red_s[1][cl] + red_s[2][cl] + red_s[3][cl];
    float q = red_q[0][cl] + red_q[1][cl] + red_q[2][cl] + red_q[3][cl];
    float m = s * (1.f / 256.f);
    float var = q * (1.f / 256.f) - m * m;
    mu[li] = m;
    rstd[li] = rsqrtf(var + 1e-5f);
  }
  // normalize in place (each thread rewrites exactly the slots it read)
  #pragma unroll
  for (int di = 0; di < 4; ++di) {
    #pragma unroll
    for (int r = 0; r < 4; ++r) {
      int d = wv * 64 + di * 16 + kgrp * 4 + r;
      float lwv = lw[d], lbv = lb[d];
      #pragma unroll
      for (int li = 0; li < 2; ++li) {
        int l = li * 16 + row16;
        rt[d * 33 + l] = (vv[di][li][r] - mu[li]) * rstd[li] * lwv + lbv;
      }
    }
  }
  __syncthreads();                           // B5: rt (normalized) visible
  if (!LAST) {
    // coalesced store: full 128B rows
    float* hw = h_buf + (size_t)b * HH * LL + l0;
    #pragma unroll
    for (int p = 0; p < 8; ++p) {
      int row = p * 32 + (t >> 3);
      int c4 = (t & 7) * 4;
      const float* src = &rt[row * 33 + c4];
      float4 v;
      v.x = src[0]; v.y = src[1]; v.z = src[2]; v.w = src[3];
      *(float4*)(hw + (size_t)row * LL + c4) = v;
    }
  } else {
    // fused decoder: out[b, dd, l0+l] = sum_d rt[d][l] * dcw[d*16+dd] + dcb[dd]
    int l = t & 31, dd = t >> 5;   // dd 0..7; thread covers dd and dd+8
    float a0 = dcb[dd], a1 = dcb[dd + 8];
    #pragma unroll 8
    for (int d = 0; d < HH; ++d) {
      float hv = rt[d * 33 + l];
      a0 = fmaf(hv, dcw[d * DIN + dd], a0);
      a1 = fmaf(hv, dcw[d * DIN + dd + 8], a1);
    }
    float* ob = outp + (size_t)b * DIN * LL + l0;
    ob[(size_t)dd * LL + l] = a0;
    ob[(size_t)(dd + 8) * LL + l] = a1;
  }
}

extern "C" void kernel_launch(void* const* d_in, const int* in_sizes, int n_in,
                              void* d_out, int out_size, void* d_ws, size_t ws_size,
                              hipStream_t stream) {
  const float* x      = (const float*)d_in[0];
  const float* enc_w  = (const float*)d_in[1];
  const float* enc_b  = (const float*)d_in[2];
  const float* log_dt = (const float*)d_in[3];
  const float* A_re   = (const float*)d_in[4];
  const float* A_im   = (const float*)d_in[5];
  const float* C_re   = (const float*)d_in[6];
  const float* C_im   = (const float*)d_in[7];
  const float* Dv     = (const float*)d_in[8];
  const float* W_out  = (const float*)d_in[9];
  const float* b_out  = (const float*)d_in[10];
  const float* ln_w   = (const float*)d_in[11];
  const float* ln_b   = (const float*)d_in[12];
  const float* dec_w  = (const float*)d_in[13];
  const float* dec_b  = (const float*)d_in[14];
  float* out = (float*)d_out;

  float* h_buf = (float*)d_ws;
  unsigned int* g_pack = (unsigned int*)(h_buf + (size_t)Bb * HH * LL);
  float* w64 = (float*)(g_pack + (size_t)Bb * HH * LL);
  unsigned int* Wp = (unsigned int*)(w64 + 2 * HN);
  u16* Bf = (u16*)(Wp + HH * HH);

  enc_kernel<<<Bb * HH * (LL / 256), 256, 0, stream>>>(x, enc_w, enc_b, h_buf);
  for (int i = 0; i < NLAY; ++i) {
    basis_kernel<<<HH, 256, 0, stream>>>(log_dt + i * HH, A_re + i * HN,
                                         A_im + i * HN, C_re + i * HN,
                                         C_im + i * HN, w64, Bf);
    wpack_kernel<<<HH * HH / 256, 256, 0, stream>>>(W_out + (size_t)i * HH * HH, Wp);
    s4_mfma_kernel<<<Bb * HH, 256, 0, stream>>>(h_buf, w64, Dv + i * HH, Bf, g_pack);
    if (i < NLAY - 1) {
      mm_mfma_ln_kernel<0><<<Bb * (LL / BN), 256, 0, stream>>>(
          g_pack, h_buf, Wp, b_out + i * HH, ln_w + i * HH, ln_b + i * HH,
          dec_w, dec_b, out);
    } else {
      mm_mfma_ln_kernel<1><<<Bb * (LL / BN), 256, 0, stream>>>(
          g_pack, h_buf, Wp, b_out + i * HH, ln_w + i * HH, ln_b + i * HH,
          dec_w, dec_b, out);
    }
  }
}

// Round 15
// 643.868 us; speedup vs baseline: 1.3849x; 1.0173x over previous
//
#include <hip/hip_runtime.h>
#include <hip/hip_bf16.h>
#include <math.h>

#define Bb 16
#define DIN 16
#define LL 4096
#define HH 256
#define NN2 32
#define NLAY 4
#define HN (HH*NN2)
#define BN 32          // mm l-tile

typedef __attribute__((ext_vector_type(8))) short short8;
typedef __attribute__((ext_vector_type(4))) short short4v;
typedef __attribute__((ext_vector_type(4))) float f32x4;
typedef unsigned short u16;

__device__ inline u16 f2bf(float f) {
  unsigned int x = __float_as_uint(f);
  unsigned int r = x + 0x7FFFu + ((x >> 16) & 1u);   // RNE
  return (u16)(r >> 16);
}
__device__ inline float bf2f(u16 u) {
  return __uint_as_float(((unsigned int)u) << 16);
}
__device__ inline unsigned int packsplit(float v) {
  u16 hi = f2bf(v);
  u16 lo = f2bf(v - bf2f(hi));
  return (((unsigned int)hi) << 16) | lo;
}
// v_cvt_pk_bf16_f32: low16 = bf16(a), high16 = bf16(b), RNE
__device__ inline unsigned int cvtpk(float a, float b) {
  unsigned int r;
  asm("v_cvt_pk_bf16_f32 %0, %1, %2" : "=v"(r) : "v"(a), "v"(b));
  return r;
}
// LDS fragment loader: 4 u16 at p, 4 u16 at p+16 (k and k+16 halves)
__device__ inline short8 ld8(const u16* p) {
  short4v a = *(const short4v*)p;
  short4v b = *(const short4v*)(p + 16);
  return __builtin_shufflevector(a, b, 0, 1, 2, 3, 4, 5, 6, 7);
}
// fragment-major index for basis matrices: m in 0..5 (Th,Tl,Mh,Ml,Eh,El)
__device__ inline size_t fidx(int h, int m, int row, int col) {
  int wv = row >> 4, row16 = row & 15;
  int kh = col >> 5, c5 = col & 31;
  int lane = ((c5 & 15) >> 2) * 16 + row16;
  int j = (((c5 >> 4) & 1) << 2) | (c5 & 3);
  return ((((((size_t)h * 6 + m) * 4 + wv) * 2 + kh) * 64 + lane) << 3) + j;
}

// ---------------- encoder ----------------
__global__ __launch_bounds__(256) void enc_kernel(const float* __restrict__ x,
    const float* __restrict__ ew, const float* __restrict__ eb,
    float* __restrict__ hbuf) {
  int blk = blockIdx.x;
  int tile = blk & 15;
  int h = (blk >> 4) & (HH - 1);
  int b = blk >> 12;
  int l = tile * 256 + threadIdx.x;
  const float* xb = x + (size_t)b * DIN * LL + l;
  float acc = eb[h];
  #pragma unroll
  for (int i = 0; i < DIN; ++i)
    acc = fmaf(xb[(size_t)i * LL], ew[i * HH + h], acc);
  hbuf[((size_t)(b * HH + h)) * LL + l] = acc;
}

// ---------------- basis (coef fused): T/M/E in fragment-major layout + w64 ----------------
__global__ __launch_bounds__(256) void basis_kernel(
    const float* __restrict__ log_dt, const float* __restrict__ Are,
    const float* __restrict__ Aim, const float* __restrict__ Cre,
    const float* __restrict__ Cim, float* __restrict__ w64,
    u16* __restrict__ Bf) {
  __shared__ float K_l[64];
  int h = blockIdx.x;
  int t = threadIdx.x;
  if (t < 32) {
    int n = t;
    int idx = h * 32 + n;
    float dt = expf(log_dt[h]);
    float ar = -expf(Are[idx]);
    float ai = Aim[idx];
    float er = expf(ar * dt);
    float wr = er * cosf(ai * dt);
    float wi = er * sinf(ai * dt);
    float nr = wr - 1.f, ni = wi;
    float inv = 1.f / (ar * ar + ai * ai);
    float qr = (nr * ar + ni * ai) * inv;
    float qi = (ni * ar - nr * ai) * inv;
    float crv = Cre[idx], civ = Cim[idx];
    float cr = 2.f * (crv * qr - civ * qi);
    float ci = 2.f * (crv * qi + civ * qr);
    // w^64 for the scan
    float pr = wr, pi = wi;
    #pragma unroll
    for (int q = 0; q < 6; ++q) {
      float t0 = pr * pr - pi * pi;
      pi = 2.f * pr * pi;
      pr = t0;
    }
    w64[idx] = pr;
    w64[HN + idx] = pi;
    // M, E, K
    float vr = 1.f, vi = 0.f;
    for (int m = 0; m <= 64; ++m) {
      float e = cr * vr - ci * vi;
      float f = -(cr * vi + ci * vr);
      float s = e;
      s += __shfl_xor(s, 1); s += __shfl_xor(s, 2); s += __shfl_xor(s, 4);
      s += __shfl_xor(s, 8); s += __shfl_xor(s, 16);
      if (m <= 63) {
        if (n == 0) K_l[m] = s;
        int i = 63 - m;
        u16 hr = f2bf(vr);
        Bf[fidx(h, 2, 2 * n, i)] = hr;
        Bf[fidx(h, 3, 2 * n, i)] = f2bf(vr - bf2f(hr));
        u16 hi2 = f2bf(vi);
        Bf[fidx(h, 2, 2 * n + 1, i)] = hi2;
        Bf[fidx(h, 3, 2 * n + 1, i)] = f2bf(vi - bf2f(hi2));
      }
      if (m >= 1) {
        int row = m - 1;
        u16 he = f2bf(e);
        Bf[fidx(h, 4, row, 2 * n)] = he;
        Bf[fidx(h, 5, row, 2 * n)] = f2bf(e - bf2f(he));
        u16 hf = f2bf(f);
        Bf[fidx(h, 4, row, 2 * n + 1)] = hf;
        Bf[fidx(h, 5, row, 2 * n + 1)] = f2bf(f - bf2f(hf));
      }
      float nvr = vr * wr - vi * wi;
      float nvi = vr * wi + vi * wr;
      vr = nvr; vi = nvi;
    }
  }
  __syncthreads();
  #pragma unroll
  for (int p = 0; p < 16; ++p) {
    int id = p * 256 + t;
    int j = id >> 6, i = id & 63;
    float kv = (j >= i) ? K_l[j - i] : 0.f;
    u16 hi = f2bf(kv);
    Bf[fidx(h, 0, j, i)] = hi;
    Bf[fidx(h, 1, j, i)] = f2bf(kv - bf2f(hi));
  }
}

// ---------------- W pack: fragment-major Wp[wv][ks][di][lane][8] ----------------
__global__ __launch_bounds__(256) void wpack_kernel(const float* __restrict__ W,
                                                    unsigned int* __restrict__ Wp) {
  int idx = blockIdx.x * 256 + threadIdx.x;   // 65536 total
  int j = idx & 7;
  int lane = (idx >> 3) & 63;
  int di = (idx >> 9) & 3;
  int ks = (idx >> 11) & 7;
  int wv = idx >> 14;
  int row16 = lane & 15, kgrp = lane >> 4;
  int d = wv * 64 + di * 16 + row16;
  int hcol = ks * 32 + kgrp * 4 + (j & 3) + ((j >> 2) << 4);
  Wp[idx] = packsplit(W[hcol * HH + d]);
}

// ---------------- MFMA SSM v3: reg-hoisted fragments, cvt_pk conversions ----------------
__global__ __launch_bounds__(256, 4) void s4_mfma_kernel(
    const float* __restrict__ zg, const float* __restrict__ w64,
    const float* __restrict__ Dvec, const u16* __restrict__ Bf,
    unsigned int* __restrict__ gout) {
  __shared__ u16 zh[64 * 68], zl[64 * 68];   // z planes [chunk][i], pad 68
  __shared__ float stT[64 * 68];             // Phase-A ends transposed; aliased later
  u16* sh = (u16*)stT;
  u16* sl = sh + 64 * 68;
  unsigned int* packbuf = (unsigned int*)stT;
  int bh = blockIdx.x, h = bh & (HH - 1), t = threadIdx.x;
  int wv = t >> 6, lane = t & 63, row16 = lane & 15, kgrp = lane >> 4;
  // hoisted A-fragment loads (coalesced 16B each), issued before staging
  const u16* BfH = Bf + (size_t)h * (6 * 4 * 2 * 64 * 8);
  #define LDF(m, kh) (*(const short8*)(BfH + (((m) * 4 + wv) * 2 + (kh)) * 512 + lane * 8))
  short8 fTh0 = LDF(0, 0), fTh1 = LDF(0, 1);
  short8 fTl0 = LDF(1, 0), fTl1 = LDF(1, 1);
  short8 fMh0 = LDF(2, 0), fMh1 = LDF(2, 1);
  short8 fMl0 = LDF(3, 0), fMl1 = LDF(3, 1);
  const float* zrow = zg + (size_t)bh * LL;
  int c0 = t >> 2, i0 = (t & 3) * 16;
  {
    const float4* zsrc = (const float4*)(zrow + c0 * 64 + i0);
    #pragma unroll
    for (int q = 0; q < 4; ++q) {
      float4 v = zsrc[q];
      unsigned int hp0 = cvtpk(v.x, v.y);
      unsigned int hp1 = cvtpk(v.z, v.w);
      float r0 = v.x - __uint_as_float(hp0 << 16);
      float r1 = v.y - __uint_as_float(hp0 & 0xFFFF0000u);
      float r2 = v.z - __uint_as_float(hp1 << 16);
      float r3 = v.w - __uint_as_float(hp1 & 0xFFFF0000u);
      unsigned int lp0 = cvtpk(r0, r1);
      unsigned int lp1 = cvtpk(r2, r3);
      int base = c0 * 68 + i0 + q * 4;
      *(unsigned int*)&zh[base] = hp0;
      *(unsigned int*)&zh[base + 2] = hp1;
      *(unsigned int*)&zl[base] = lp0;
      *(unsigned int*)&zl[base + 2] = lp1;
    }
  }
  __syncthreads();                                         // B1
  f32x4 y[4];
  // ---- Phase A: S_end = M@Z (stT transposed) and y = T@Z, shared z frags ----
  #pragma unroll
  for (int ct = 0; ct < 4; ++ct) {
    f32x4 aS = (f32x4){0.f, 0.f, 0.f, 0.f};
    f32x4 aY = (f32x4){0.f, 0.f, 0.f, 0.f};
    int cc = ct * 16 + row16;
    #pragma unroll
    for (int kh = 0; kh < 2; ++kh) {
      int kb = kh * 32 + kgrp * 4;
      short8 Bh = ld8(&zh[cc * 68 + kb]);
      short8 Bl = ld8(&zl[cc * 68 + kb]);
      short8 Ah = kh ? fMh1 : fMh0;
      short8 Al = kh ? fMl1 : fMl0;
      aS = __builtin_amdgcn_mfma_f32_16x16x32_bf16(Ah, Bh, aS, 0, 0, 0);
      aS = __builtin_amdgcn_mfma_f32_16x16x32_bf16(Ah, Bl, aS, 0, 0, 0);
      aS = __builtin_amdgcn_mfma_f32_16x16x32_bf16(Al, Bh, aS, 0, 0, 0);
      short8 Ch = kh ? fTh1 : fTh0;
      short8 Cl = kh ? fTl1 : fTl0;
      aY = __builtin_amdgcn_mfma_f32_16x16x32_bf16(Ch, Bh, aY, 0, 0, 0);
      aY = __builtin_amdgcn_mfma_f32_16x16x32_bf16(Ch, Bl, aY, 0, 0, 0);
      aY = __builtin_amdgcn_mfma_f32_16x16x32_bf16(Cl, Bh, aY, 0, 0, 0);
    }
    y[ct] = aY;
    #pragma unroll
    for (int r = 0; r < 4; ++r)
      stT[(wv * 16 + kgrp * 4 + r) * 68 + cc] = aS[r];
  }
  __syncthreads();                                         // B2
  // E fragments: load now so latency overlaps the scan
  short8 fEh0 = LDF(4, 0), fEh1 = LDF(4, 1);
  short8 fEl0 = LDF(5, 0), fEl1 = LDF(5, 1);
  #undef LDF
  // ---- wave-shuffle scan: lane = chunk, wave wv owns states n = wv*8..wv*8+7 ----
  float ir[8], ii[8];
  {
    float xr[8], xi[8], pr[8], pi[8];
    #pragma unroll
    for (int k = 0; k < 8; ++k) {
      int d0 = wv * 16 + 2 * k;
      xr[k] = stT[d0 * 68 + lane];
      xi[k] = stT[(d0 + 1) * 68 + lane];
      pr[k] = w64[h * 32 + wv * 8 + k];
      pi[k] = w64[HN + h * 32 + wv * 8 + k];
    }
    #pragma unroll
    for (int d = 1; d < 64; d <<= 1) {
      #pragma unroll
      for (int k = 0; k < 8; ++k) {
        float qr = __shfl_up(xr[k], d);
        float qi = __shfl_up(xi[k], d);
        if (lane >= d) {
          xr[k] = fmaf(pr[k], qr, fmaf(-pi[k], qi, xr[k]));
          xi[k] = fmaf(pr[k], qi, fmaf(pi[k], qr, xi[k]));
        }
        float t0 = pr[k] * pr[k] - pi[k] * pi[k];
        pi[k] = 2.f * pr[k] * pi[k];
        pr[k] = t0;
      }
    }
    #pragma unroll
    for (int k = 0; k < 8; ++k) {
      ir[k] = __shfl_up(xr[k], 1);
      ii[k] = __shfl_up(xi[k], 1);
      if (lane == 0) { ir[k] = 0.f; ii[k] = 0.f; }
    }
  }
  __syncthreads();                                         // B3 (stT reads done)
  #pragma unroll
  for (int k = 0; k < 8; ++k) {
    int d0 = wv * 16 + 2 * k;
    unsigned int hp = cvtpk(ir[k], ii[k]);
    float rr = ir[k] - __uint_as_float(hp << 16);
    float ri = ii[k] - __uint_as_float(hp & 0xFFFF0000u);
    unsigned int lp = cvtpk(rr, ri);
    *(unsigned int*)&sh[lane * 68 + d0] = hp;
    *(unsigned int*)&sl[lane * 68 + d0] = lp;
  }
  __syncthreads();                                         // B4
  // ---- Phase B: y += E @ S_init ----
  #pragma unroll
  for (int ct = 0; ct < 4; ++ct) {
    f32x4 a = y[ct];
    int cc = ct * 16 + row16;
    #pragma unroll
    for (int kh = 0; kh < 2; ++kh) {
      int kb = kh * 32 + kgrp * 4;
      short8 Sh8 = ld8(&sh[cc * 68 + kb]);
      short8 Sl8 = ld8(&sl[cc * 68 + kb]);
      short8 Ah = kh ? fEh1 : fEh0;
      short8 Al = kh ? fEl1 : fEl0;
      a = __builtin_amdgcn_mfma_f32_16x16x32_bf16(Ah, Sh8, a, 0, 0, 0);
      a = __builtin_amdgcn_mfma_f32_16x16x32_bf16(Ah, Sl8, a, 0, 0, 0);
      a = __builtin_amdgcn_mfma_f32_16x16x32_bf16(Al, Sh8, a, 0, 0, 0);
    }
    y[ct] = a;
  }
  __syncthreads();                                         // B5
  // ---- epilogue: v = z*D + y, gelu, pack (cvt_pk), uint4 into aliased buffer ----
  {
    float Dh = Dvec[h];
    int j0 = wv * 16 + kgrp * 4;
    #pragma unroll
    for (int ct = 0; ct < 4; ++ct) {
      int cc = ct * 16 + row16;
      unsigned int za = *(const unsigned int*)&zh[cc * 68 + j0];
      unsigned int zb = *(const unsigned int*)&zh[cc * 68 + j0 + 2];
      unsigned int la = *(const unsigned int*)&zl[cc * 68 + j0];
      unsigned int lb = *(const unsigned int*)&zl[cc * 68 + j0 + 2];
      float zf[4];
      zf[0] = __uint_as_float(za << 16) + __uint_as_float(la << 16);
      zf[1] = __uint_as_float(za & 0xFFFF0000u) + __uint_as_float(la & 0xFFFF0000u);
      zf[2] = __uint_as_float(zb << 16) + __uint_as_float(lb << 16);
      zf[3] = __uint_as_float(zb & 0xFFFF0000u) + __uint_as_float(lb & 0xFFFF0000u);
      float v[4];
      #pragma unroll
      for (int r = 0; r < 4; ++r) {
        float vv = fmaf(zf[r], Dh, y[ct][r]);
        float u = 1.5957691216057308f * fmaf(0.044715f * vv, vv * vv, vv);
        v[r] = vv / (1.f + __expf(-u));
      }
      unsigned int h01 = cvtpk(v[0], v[1]);
      unsigned int h23 = cvtpk(v[2], v[3]);
      float r0 = v[0] - __uint_as_float(h01 << 16);
      float r1 = v[1] - __uint_as_float(h01 & 0xFFFF0000u);
      float r2 = v[2] - __uint_as_float(h23 << 16);
      float r3 = v[3] - __uint_as_float(h23 & 0xFFFF0000u);
      unsigned int l01 = cvtpk(r0, r1);
      unsigned int l23 = cvtpk(r2, r3);
      uint4 w;
      w.x = (h01 << 16) | (l01 & 0xFFFFu);
      w.y = (h01 & 0xFFFF0000u) | (l01 >> 16);
      w.z = (h23 << 16) | (l23 & 0xFFFFu);
      w.w = (h23 & 0xFFFF0000u) | (l23 >> 16);
      *(uint4*)&packbuf[cc * 68 + j0] = w;
    }
  }
  __syncthreads();                                         // B6
  {
    unsigned int* grow = gout + (size_t)bh * LL;
    #pragma unroll
    for (int q = 0; q < 4; ++q) {
      uint4 v = *(const uint4*)&packbuf[c0 * 68 + i0 + q * 4];
      *(uint4*)&grow[c0 * 64 + i0 + q * 4] = v;
    }
  }
}

// ---------------- MFMA matmul + bias + residual + LayerNorm (fragment-major W) ----------------
// template<LAST>: last layer fuses the decoder (reads normalized tile from LDS).
template<int LAST>
__global__ __launch_bounds__(256, 4) void mm_mfma_ln_kernel(
    const unsigned int* __restrict__ gp, float* __restrict__ h_buf,
    const unsigned int* __restrict__ Wp, const float* __restrict__ bo,
    const float* __restrict__ lw, const float* __restrict__ lb,
    const float* __restrict__ dcw, const float* __restrict__ dcb,
    float* __restrict__ outp) {
  __shared__ float smem[HH * 33];            // gt (first 32KB); LAST also uses as rt
  __shared__ float red_s[4][BN];
  __shared__ float red_q[4][BN];
  unsigned int* gt = (unsigned int*)smem;
  float* rt = smem;
  int blk = blockIdx.x;
  int b = blk >> 7;
  int l0 = (blk & 127) * BN;
  int t = threadIdx.x;
  const unsigned int* gbase = gp + (size_t)b * HH * LL + l0;
  #pragma unroll
  for (int p = 0; p < 4; ++p) {
    int hh = p * 64 + (t >> 2);
    int lq = (t & 3) * 8;
    const uint4* src = (const uint4*)(gbase + (size_t)hh * LL + lq);
    uint4 v0 = src[0];
    uint4 v1 = src[1];
    unsigned int vals[8] = {v0.x, v0.y, v0.z, v0.w, v1.x, v1.y, v1.z, v1.w};
    #pragma unroll
    for (int j = 0; j < 8; ++j) {
      int l = lq + j;
      int xm = (l & 7) ^ ((l >> 3) & 3);
      int g4 = (hh >> 2) ^ xm;
      gt[l * HH + g4 * 4 + (hh & 3)] = vals[j];
    }
  }
  __syncthreads();
  int wv = t >> 6, lane = t & 63;
  int row16 = lane & 15, kgrp = lane >> 4;
  f32x4 acc[4][2];
  #pragma unroll
  for (int di = 0; di < 4; ++di)
    #pragma unroll
    for (int li = 0; li < 2; ++li)
      acc[di][li] = (f32x4){0.f, 0.f, 0.f, 0.f};
  #pragma unroll 2
  for (int ks = 0; ks < 8; ++ks) {
    int h0 = ks * 32;
    short8 Bhi[2], Blo[2];
    #pragma unroll
    for (int li = 0; li < 2; ++li) {
      int l = li * 16 + row16;
      int xm = (l & 7) ^ ((l >> 3) & 3);
      int g4a = ((h0 >> 2) + kgrp) ^ xm;
      int g4b = ((h0 >> 2) + kgrp + 4) ^ xm;
      uint4 pa = *(const uint4*)&gt[l * HH + g4a * 4];
      uint4 pb = *(const uint4*)&gt[l * HH + g4b * 4];
      union { int i[4]; short8 s; } uh, ul;
      uh.i[0] = (int)((pa.x >> 16) | (pa.y & 0xFFFF0000u));
      uh.i[1] = (int)((pa.z >> 16) | (pa.w & 0xFFFF0000u));
      uh.i[2] = (int)((pb.x >> 16) | (pb.y & 0xFFFF0000u));
      uh.i[3] = (int)((pb.z >> 16) | (pb.w & 0xFFFF0000u));
      ul.i[0] = (int)((pa.x & 0xFFFFu) | (pa.y << 16));
      ul.i[1] = (int)((pa.z & 0xFFFFu) | (pa.w << 16));
      ul.i[2] = (int)((pb.x & 0xFFFFu) | (pb.y << 16));
      ul.i[3] = (int)((pb.z & 0xFFFFu) | (pb.w << 16));
      Bhi[li] = uh.s; Blo[li] = ul.s;
    }
    #pragma unroll
    for (int di = 0; di < 4; ++di) {
      const uint4* wf = (const uint4*)Wp + ((((wv * 8 + ks) * 4 + di) * 64 + lane) * 2);
      uint4 pa = wf[0];
      uint4 pb = wf[1];
      union { int i[4]; short8 s; } uh, ul;
      uh.i[0] = (int)((pa.x >> 16) | (pa.y & 0xFFFF0000u));
      uh.i[1] = (int)((pa.z >> 16) | (pa.w & 0xFFFF0000u));
      uh.i[2] = (int)((pb.x >> 16) | (pb.y & 0xFFFF0000u));
      uh.i[3] = (int)((pb.z >> 16) | (pb.w & 0xFFFF0000u));
      ul.i[0] = (int)((pa.x & 0xFFFFu) | (pa.y << 16));
      ul.i[1] = (int)((pa.z & 0xFFFFu) | (pa.w << 16));
      ul.i[2] = (int)((pb.x & 0xFFFFu) | (pb.y << 16));
      ul.i[3] = (int)((pb.z & 0xFFFFu) | (pb.w << 16));
      short8 Ahi = uh.s, Alo = ul.s;
      #pragma unroll
      for (int li = 0; li < 2; ++li) {
        acc[di][li] = __builtin_amdgcn_mfma_f32_16x16x32_bf16(Ahi, Bhi[li], acc[di][li], 0, 0, 0);
        acc[di][li] = __builtin_amdgcn_mfma_f32_16x16x32_bf16(Ahi, Blo[li], acc[di][li], 0, 0, 0);
        acc[di][li] = __builtin_amdgcn_mfma_f32_16x16x32_bf16(Alo, Bhi[li], acc[di][li], 0, 0, 0);
      }
    }
  }
  const float* hb = h_buf + (size_t)b * HH * LL + l0;
  #pragma unroll
  for (int di = 0; di < 4; ++di) {
    #pragma unroll
    for (int r = 0; r < 4; ++r) {
      int d = wv * 64 + di * 16 + kgrp * 4 + r;
      float bov = bo[d];
      #pragma unroll
      for (int li = 0; li < 2; ++li) {
        int l = li * 16 + row16;
        acc[di][li][r] += bov + hb[(size_t)d * LL + l];
      }
    }
  }
  #pragma unroll
  for (int li = 0; li < 2; ++li) {
    float s = 0.f, q = 0.f;
    #pragma unroll
    for (int di = 0; di < 4; ++di)
      #pragma unroll
      for (int r = 0; r < 4; ++r) {
        float v = acc[di][li][r];
        s += v;
        q = fmaf(v, v, q);
      }
    s += __shfl_xor(s, 16); s += __shfl_xor(s, 32);
    q += __shfl_xor(q, 16); q += __shfl_xor(q, 32);
    if (lane < 16) {
      red_s[wv][li * 16 + lane] = s;
      red_q[wv][li * 16 + lane] = q;
    }
  }
  __syncthreads();   // red visible; also all gt reads complete (K-loop is before)
  float mu[2], rstd[2];
  #pragma unroll
  for (int li = 0; li < 2; ++li) {
    int cl = li * 16 + row16;
    float s = red_s[0][cl] + red_s[1][cl] + red_s[2][cl] + red_s[3][cl];
    float q = red_q[0][cl] + red_q[1][cl] + red_q[2][cl] + red_q[3][cl];
    float m = s * (1.f / 256.f);
    float var = q * (1.f / 256.f) - m * m;
    mu[li] = m;
    rstd[li] = rsqrtf(var + 1e-5f);
  }
  if (!LAST) {
    float* hw = h_buf + (size_t)b * HH * LL + l0;
    #pragma unroll
    for (int di = 0; di < 4; ++di) {
      #pragma unroll
      for (int r = 0; r < 4; ++r) {
        int d = wv * 64 + di * 16 + kgrp * 4 + r;
        float lwv = lw[d], lbv = lb[d];
        #pragma unroll
        for (int li = 0; li < 2; ++li) {
          int l = li * 16 + row16;
          hw[(size_t)d * LL + l] = (acc[di][li][r] - mu[li]) * rstd[li] * lwv + lbv;
        }
      }
    }
  } else {
    // route normalized tile through LDS (gt dead), then fused decoder
    #pragma unroll
    for (int di = 0; di < 4; ++di) {
      #pragma unroll
      for (int r = 0; r < 4; ++r) {
        int d = wv * 64 + di * 16 + kgrp * 4 + r;
        float lwv = lw[d], lbv = lb[d];
        #pragma unroll
        for (int li = 0; li < 2; ++li) {
          int l = li * 16 + row16;
          rt[d * 33 + l] = (acc[di][li][r] - mu[li]) * rstd[li] * lwv + lbv;
        }
      }
    }
    __syncthreads();
    int l = t & 31, dd = t >> 5;   // dd 0..7; thread covers dd and dd+8
    float a0 = dcb[dd], a1 = dcb[dd + 8];
    #pragma unroll 8
    for (int d = 0; d < HH; ++d) {
      float hv = rt[d * 33 + l];
      a0 = fmaf(hv, dcw[d * DIN + dd], a0);
      a1 = fmaf(hv, dcw[d * DIN + dd + 8], a1);
    }
    float* ob = outp + (size_t)b * DIN * LL + l0;
    ob[(size_t)dd * LL + l] = a0;
    ob[(size_t)(dd + 8) * LL + l] = a1;
  }
}

extern "C" void kernel_launch(void* const* d_in, const int* in_sizes, int n_in,
                              void* d_out, int out_size, void* d_ws, size_t ws_size,
                              hipStream_t stream) {
  const float* x      = (const float*)d_in[0];
  const float* enc_w  = (const float*)d_in[1];
  const float* enc_b  = (const float*)d_in[2];
  const float* log_dt = (const float*)d_in[3];
  const float* A_re   = (const float*)d_in[4];
  const float* A_im   = (const float*)d_in[5];
  const float* C_re   = (const float*)d_in[6];
  const float* C_im   = (const float*)d_in[7];
  const float* Dv     = (const float*)d_in[8];
  const float* W_out  = (const float*)d_in[9];
  const float* b_out  = (const float*)d_in[10];
  const float* ln_w   = (const float*)d_in[11];
  const float* ln_b   = (const float*)d_in[12];
  const float* dec_w  = (const float*)d_in[13];
  const float* dec_b  = (const float*)d_in[14];
  float* out = (float*)d_out;

  float* h_buf = (float*)d_ws;
  unsigned int* g_pack = (unsigned int*)(h_buf + (size_t)Bb * HH * LL);
  float* w64 = (float*)(g_pack + (size_t)Bb * HH * LL);
  unsigned int* Wp = (unsigned int*)(w64 + 2 * HN);
  u16* Bf = (u16*)(Wp + HH * HH);

  enc_kernel<<<Bb * HH * (LL / 256), 256, 0, stream>>>(x, enc_w, enc_b, h_buf);
  for (int i = 0; i < NLAY; ++i) {
    basis_kernel<<<HH, 256, 0, stream>>>(log_dt + i * HH, A_re + i * HN,
                                         A_im + i * HN, C_re + i * HN,
                                         C_im + i * HN, w64, Bf);
    wpack_kernel<<<HH * HH / 256, 256, 0, stream>>>(W_out + (size_t)i * HH * HH, Wp);
    s4_mfma_kernel<<<Bb * HH, 256, 0, stream>>>(h_buf, w64, Dv + i * HH, Bf, g_pack);
    if (i < NLAY - 1) {
      mm_mfma_ln_kernel<0><<<Bb * (LL / BN), 256, 0, stream>>>(
          g_pack, h_buf, Wp, b_out + i * HH, ln_w + i * HH, ln_b + i * HH,
          dec_w, dec_b, out);
    } else {
      mm_mfma_ln_kernel<1><<<Bb * (LL / BN), 256, 0, stream>>>(
          g_pack, h_buf, Wp, b_out + i * HH, ln_w + i * HH, ln_b + i * HH,
          dec_w, dec_b, out);
    }
  }
}

// Round 16
// 627.615 us; speedup vs baseline: 1.4208x; 1.0259x over previous
//
#include <hip/hip_runtime.h>
#include <hip/hip_bf16.h>
#include <math.h>

#define Bb 16
#define DIN 16
#define LL 4096
#define HH 256
#define NN2 32
#define NLAY 4
#define HN (HH*NN2)
#define BN 32          // mm l-tile

typedef __attribute__((ext_vector_type(8))) short short8;
typedef __attribute__((ext_vector_type(4))) short short4v;
typedef __attribute__((ext_vector_type(4))) float f32x4;
typedef unsigned short u16;

__device__ inline u16 f2bf(float f) {
  unsigned int x = __float_as_uint(f);
  unsigned int r = x + 0x7FFFu + ((x >> 16) & 1u);   // RNE
  return (u16)(r >> 16);
}
__device__ inline float bf2f(u16 u) {
  return __uint_as_float(((unsigned int)u) << 16);
}
__device__ inline unsigned int packsplit(float v) {
  u16 hi = f2bf(v);
  u16 lo = f2bf(v - bf2f(hi));
  return (((unsigned int)hi) << 16) | lo;
}
// v_cvt_pk_bf16_f32: low16 = bf16(a), high16 = bf16(b), RNE
__device__ inline unsigned int cvtpk(float a, float b) {
  unsigned int r;
  asm("v_cvt_pk_bf16_f32 %0, %1, %2" : "=v"(r) : "v"(a), "v"(b));
  return r;
}
// LDS fragment loader: 4 u16 at p, 4 u16 at p+16 (k and k+16 halves)
__device__ inline short8 ld8(const u16* p) {
  short4v a = *(const short4v*)p;
  short4v b = *(const short4v*)(p + 16);
  return __builtin_shufflevector(a, b, 0, 1, 2, 3, 4, 5, 6, 7);
}
// fragment-major index for basis matrices: m in 0..5 (Th,Tl,Mh,Ml,Eh,El)
__device__ inline size_t fidx(int h, int m, int row, int col) {
  int wv = row >> 4, row16 = row & 15;
  int kh = col >> 5, c5 = col & 31;
  int lane = ((c5 & 15) >> 2) * 16 + row16;
  int j = (((c5 >> 4) & 1) << 2) | (c5 & 3);
  return ((((((size_t)h * 6 + m) * 4 + wv) * 2 + kh) * 64 + lane) << 3) + j;
}

// ---------------- encoder ----------------
__global__ __launch_bounds__(256) void enc_kernel(const float* __restrict__ x,
    const float* __restrict__ ew, const float* __restrict__ eb,
    float* __restrict__ hbuf) {
  int blk = blockIdx.x;
  int tile = blk & 15;
  int h = (blk >> 4) & (HH - 1);
  int b = blk >> 12;
  int l = tile * 256 + threadIdx.x;
  const float* xb = x + (size_t)b * DIN * LL + l;
  float acc = eb[h];
  #pragma unroll
  for (int i = 0; i < DIN; ++i)
    acc = fmaf(xb[(size_t)i * LL], ew[i * HH + h], acc);
  hbuf[((size_t)(b * HH + h)) * LL + l] = acc;
}

// ---------------- prep: basis (blocks 0..255) + W pack (blocks 256..511) ----------------
// Merged launch (R13-validated component): disjoint outputs, no cross-path barriers.
__global__ __launch_bounds__(256) void prep_kernel(
    const float* __restrict__ log_dt, const float* __restrict__ Are,
    const float* __restrict__ Aim, const float* __restrict__ Cre,
    const float* __restrict__ Cim, float* __restrict__ w64,
    u16* __restrict__ Bf, const float* __restrict__ W,
    unsigned int* __restrict__ Wp) {
  int t = threadIdx.x;
  if (blockIdx.x >= HH) {
    // ---- wpack: fragment-major Wp[wv][ks][di][lane][8] ----
    int idx = (blockIdx.x - HH) * 256 + t;
    int j = idx & 7;
    int lane = (idx >> 3) & 63;
    int di = (idx >> 9) & 3;
    int ks = (idx >> 11) & 7;
    int wv = idx >> 14;
    int row16 = lane & 15, kgrp = lane >> 4;
    int d = wv * 64 + di * 16 + row16;
    int hcol = ks * 32 + kgrp * 4 + (j & 3) + ((j >> 2) << 4);
    Wp[idx] = packsplit(W[hcol * HH + d]);
    return;
  }
  // ---- basis: T/M/E fragment-major + w64 ----
  __shared__ float K_l[64];
  int h = blockIdx.x;
  if (t < 32) {
    int n = t;
    int idx = h * 32 + n;
    float dt = expf(log_dt[h]);
    float ar = -expf(Are[idx]);
    float ai = Aim[idx];
    float er = expf(ar * dt);
    float wr = er * cosf(ai * dt);
    float wi = er * sinf(ai * dt);
    float nr = wr - 1.f, ni = wi;
    float inv = 1.f / (ar * ar + ai * ai);
    float qr = (nr * ar + ni * ai) * inv;
    float qi = (ni * ar - nr * ai) * inv;
    float crv = Cre[idx], civ = Cim[idx];
    float cr = 2.f * (crv * qr - civ * qi);
    float ci = 2.f * (crv * qi + civ * qr);
    // w^64 for the scan
    float pr = wr, pi = wi;
    #pragma unroll
    for (int q = 0; q < 6; ++q) {
      float t0 = pr * pr - pi * pi;
      pi = 2.f * pr * pi;
      pr = t0;
    }
    w64[idx] = pr;
    w64[HN + idx] = pi;
    // M, E, K
    float vr = 1.f, vi = 0.f;
    for (int m = 0; m <= 64; ++m) {
      float e = cr * vr - ci * vi;
      float f = -(cr * vi + ci * vr);
      float s = e;
      s += __shfl_xor(s, 1); s += __shfl_xor(s, 2); s += __shfl_xor(s, 4);
      s += __shfl_xor(s, 8); s += __shfl_xor(s, 16);
      if (m <= 63) {
        if (n == 0) K_l[m] = s;
        int i = 63 - m;
        u16 hr = f2bf(vr);
        Bf[fidx(h, 2, 2 * n, i)] = hr;
        Bf[fidx(h, 3, 2 * n, i)] = f2bf(vr - bf2f(hr));
        u16 hi2 = f2bf(vi);
        Bf[fidx(h, 2, 2 * n + 1, i)] = hi2;
        Bf[fidx(h, 3, 2 * n + 1, i)] = f2bf(vi - bf2f(hi2));
      }
      if (m >= 1) {
        int row = m - 1;
        u16 he = f2bf(e);
        Bf[fidx(h, 4, row, 2 * n)] = he;
        Bf[fidx(h, 5, row, 2 * n)] = f2bf(e - bf2f(he));
        u16 hf = f2bf(f);
        Bf[fidx(h, 4, row, 2 * n + 1)] = hf;
        Bf[fidx(h, 5, row, 2 * n + 1)] = f2bf(f - bf2f(hf));
      }
      float nvr = vr * wr - vi * wi;
      float nvi = vr * wi + vi * wr;
      vr = nvr; vi = nvi;
    }
  }
  __syncthreads();
  #pragma unroll
  for (int p = 0; p < 16; ++p) {
    int id = p * 256 + t;
    int j = id >> 6, i = id & 63;
    float kv = (j >= i) ? K_l[j - i] : 0.f;
    u16 hi = f2bf(kv);
    Bf[fidx(h, 0, j, i)] = hi;
    Bf[fidx(h, 1, j, i)] = f2bf(kv - bf2f(hi));
  }
}

// ---------------- MFMA SSM v3: reg-hoisted fragments, cvt_pk conversions (champion verbatim) ----------------
__global__ __launch_bounds__(256, 4) void s4_mfma_kernel(
    const float* __restrict__ zg, const float* __restrict__ w64,
    const float* __restrict__ Dvec, const u16* __restrict__ Bf,
    unsigned int* __restrict__ gout) {
  __shared__ u16 zh[64 * 68], zl[64 * 68];   // z planes [chunk][i], pad 68
  __shared__ float stT[64 * 68];             // Phase-A ends transposed; aliased later
  u16* sh = (u16*)stT;
  u16* sl = sh + 64 * 68;
  unsigned int* packbuf = (unsigned int*)stT;
  int bh = blockIdx.x, h = bh & (HH - 1), t = threadIdx.x;
  int wv = t >> 6, lane = t & 63, row16 = lane & 15, kgrp = lane >> 4;
  // hoisted A-fragment loads (coalesced 16B each), issued before staging
  const u16* BfH = Bf + (size_t)h * (6 * 4 * 2 * 64 * 8);
  #define LDF(m, kh) (*(const short8*)(BfH + (((m) * 4 + wv) * 2 + (kh)) * 512 + lane * 8))
  short8 fTh0 = LDF(0, 0), fTh1 = LDF(0, 1);
  short8 fTl0 = LDF(1, 0), fTl1 = LDF(1, 1);
  short8 fMh0 = LDF(2, 0), fMh1 = LDF(2, 1);
  short8 fMl0 = LDF(3, 0), fMl1 = LDF(3, 1);
  const float* zrow = zg + (size_t)bh * LL;
  int c0 = t >> 2, i0 = (t & 3) * 16;
  {
    const float4* zsrc = (const float4*)(zrow + c0 * 64 + i0);
    #pragma unroll
    for (int q = 0; q < 4; ++q) {
      float4 v = zsrc[q];
      unsigned int hp0 = cvtpk(v.x, v.y);
      unsigned int hp1 = cvtpk(v.z, v.w);
      float r0 = v.x - __uint_as_float(hp0 << 16);
      float r1 = v.y - __uint_as_float(hp0 & 0xFFFF0000u);
      float r2 = v.z - __uint_as_float(hp1 << 16);
      float r3 = v.w - __uint_as_float(hp1 & 0xFFFF0000u);
      unsigned int lp0 = cvtpk(r0, r1);
      unsigned int lp1 = cvtpk(r2, r3);
      int base = c0 * 68 + i0 + q * 4;
      *(unsigned int*)&zh[base] = hp0;
      *(unsigned int*)&zh[base + 2] = hp1;
      *(unsigned int*)&zl[base] = lp0;
      *(unsigned int*)&zl[base + 2] = lp1;
    }
  }
  __syncthreads();                                         // B1
  f32x4 y[4];
  // ---- Phase A: S_end = M@Z (stT transposed) and y = T@Z, shared z frags ----
  #pragma unroll
  for (int ct = 0; ct < 4; ++ct) {
    f32x4 aS = (f32x4){0.f, 0.f, 0.f, 0.f};
    f32x4 aY = (f32x4){0.f, 0.f, 0.f, 0.f};
    int cc = ct * 16 + row16;
    #pragma unroll
    for (int kh = 0; kh < 2; ++kh) {
      int kb = kh * 32 + kgrp * 4;
      short8 Bh = ld8(&zh[cc * 68 + kb]);
      short8 Bl = ld8(&zl[cc * 68 + kb]);
      short8 Ah = kh ? fMh1 : fMh0;
      short8 Al = kh ? fMl1 : fMl0;
      aS = __builtin_amdgcn_mfma_f32_16x16x32_bf16(Ah, Bh, aS, 0, 0, 0);
      aS = __builtin_amdgcn_mfma_f32_16x16x32_bf16(Ah, Bl, aS, 0, 0, 0);
      aS = __builtin_amdgcn_mfma_f32_16x16x32_bf16(Al, Bh, aS, 0, 0, 0);
      short8 Ch = kh ? fTh1 : fTh0;
      short8 Cl = kh ? fTl1 : fTl0;
      aY = __builtin_amdgcn_mfma_f32_16x16x32_bf16(Ch, Bh, aY, 0, 0, 0);
      aY = __builtin_amdgcn_mfma_f32_16x16x32_bf16(Ch, Bl, aY, 0, 0, 0);
      aY = __builtin_amdgcn_mfma_f32_16x16x32_bf16(Cl, Bh, aY, 0, 0, 0);
    }
    y[ct] = aY;
    #pragma unroll
    for (int r = 0; r < 4; ++r)
      stT[(wv * 16 + kgrp * 4 + r) * 68 + cc] = aS[r];
  }
  __syncthreads();                                         // B2
  // E fragments: load now so latency overlaps the scan
  short8 fEh0 = LDF(4, 0), fEh1 = LDF(4, 1);
  short8 fEl0 = LDF(5, 0), fEl1 = LDF(5, 1);
  #undef LDF
  // ---- wave-shuffle scan: lane = chunk, wave wv owns states n = wv*8..wv*8+7 ----
  float ir[8], ii[8];
  {
    float xr[8], xi[8], pr[8], pi[8];
    #pragma unroll
    for (int k = 0; k < 8; ++k) {
      int d0 = wv * 16 + 2 * k;
      xr[k] = stT[d0 * 68 + lane];
      xi[k] = stT[(d0 + 1) * 68 + lane];
      pr[k] = w64[h * 32 + wv * 8 + k];
      pi[k] = w64[HN + h * 32 + wv * 8 + k];
    }
    #pragma unroll
    for (int d = 1; d < 64; d <<= 1) {
      #pragma unroll
      for (int k = 0; k < 8; ++k) {
        float qr = __shfl_up(xr[k], d);
        float qi = __shfl_up(xi[k], d);
        if (lane >= d) {
          xr[k] = fmaf(pr[k], qr, fmaf(-pi[k], qi, xr[k]));
          xi[k] = fmaf(pr[k], qi, fmaf(pi[k], qr, xi[k]));
        }
        float t0 = pr[k] * pr[k] - pi[k] * pi[k];
        pi[k] = 2.f * pr[k] * pi[k];
        pr[k] = t0;
      }
    }
    #pragma unroll
    for (int k = 0; k < 8; ++k) {
      ir[k] = __shfl_up(xr[k], 1);
      ii[k] = __shfl_up(xi[k], 1);
      if (lane == 0) { ir[k] = 0.f; ii[k] = 0.f; }
    }
  }
  __syncthreads();                                         // B3 (stT reads done)
  #pragma unroll
  for (int k = 0; k < 8; ++k) {
    int d0 = wv * 16 + 2 * k;
    unsigned int hp = cvtpk(ir[k], ii[k]);
    float rr = ir[k] - __uint_as_float(hp << 16);
    float ri = ii[k] - __uint_as_float(hp & 0xFFFF0000u);
    unsigned int lp = cvtpk(rr, ri);
    *(unsigned int*)&sh[lane * 68 + d0] = hp;
    *(unsigned int*)&sl[lane * 68 + d0] = lp;
  }
  __syncthreads();                                         // B4
  // ---- Phase B: y += E @ S_init ----
  #pragma unroll
  for (int ct = 0; ct < 4; ++ct) {
    f32x4 a = y[ct];
    int cc = ct * 16 + row16;
    #pragma unroll
    for (int kh = 0; kh < 2; ++kh) {
      int kb = kh * 32 + kgrp * 4;
      short8 Sh8 = ld8(&sh[cc * 68 + kb]);
      short8 Sl8 = ld8(&sl[cc * 68 + kb]);
      short8 Ah = kh ? fEh1 : fEh0;
      short8 Al = kh ? fEl1 : fEl0;
      a = __builtin_amdgcn_mfma_f32_16x16x32_bf16(Ah, Sh8, a, 0, 0, 0);
      a = __builtin_amdgcn_mfma_f32_16x16x32_bf16(Ah, Sl8, a, 0, 0, 0);
      a = __builtin_amdgcn_mfma_f32_16x16x32_bf16(Al, Sh8, a, 0, 0, 0);
    }
    y[ct] = a;
  }
  __syncthreads();                                         // B5
  // ---- epilogue: v = z*D + y, gelu, pack (cvt_pk), uint4 into aliased buffer ----
  {
    float Dh = Dvec[h];
    int j0 = wv * 16 + kgrp * 4;
    #pragma unroll
    for (int ct = 0; ct < 4; ++ct) {
      int cc = ct * 16 + row16;
      unsigned int za = *(const unsigned int*)&zh[cc * 68 + j0];
      unsigned int zb = *(const unsigned int*)&zh[cc * 68 + j0 + 2];
      unsigned int la = *(const unsigned int*)&zl[cc * 68 + j0];
      unsigned int lb = *(const unsigned int*)&zl[cc * 68 + j0 + 2];
      float zf[4];
      zf[0] = __uint_as_float(za << 16) + __uint_as_float(la << 16);
      zf[1] = __uint_as_float(za & 0xFFFF0000u) + __uint_as_float(la & 0xFFFF0000u);
      zf[2] = __uint_as_float(zb << 16) + __uint_as_float(lb << 16);
      zf[3] = __uint_as_float(zb & 0xFFFF0000u) + __uint_as_float(lb & 0xFFFF0000u);
      float v[4];
      #pragma unroll
      for (int r = 0; r < 4; ++r) {
        float vv = fmaf(zf[r], Dh, y[ct][r]);
        float u = 1.5957691216057308f * fmaf(0.044715f * vv, vv * vv, vv);
        v[r] = vv / (1.f + __expf(-u));
      }
      unsigned int h01 = cvtpk(v[0], v[1]);
      unsigned int h23 = cvtpk(v[2], v[3]);
      float r0 = v[0] - __uint_as_float(h01 << 16);
      float r1 = v[1] - __uint_as_float(h01 & 0xFFFF0000u);
      float r2 = v[2] - __uint_as_float(h23 << 16);
      float r3 = v[3] - __uint_as_float(h23 & 0xFFFF0000u);
      unsigned int l01 = cvtpk(r0, r1);
      unsigned int l23 = cvtpk(r2, r3);
      uint4 w;
      w.x = (h01 << 16) | (l01 & 0xFFFFu);
      w.y = (h01 & 0xFFFF0000u) | (l01 >> 16);
      w.z = (h23 << 16) | (l23 & 0xFFFFu);
      w.w = (h23 & 0xFFFF0000u) | (l23 >> 16);
      *(uint4*)&packbuf[cc * 68 + j0] = w;
    }
  }
  __syncthreads();                                         // B6
  {
    unsigned int* grow = gout + (size_t)bh * LL;
    #pragma unroll
    for (int q = 0; q < 4; ++q) {
      uint4 v = *(const uint4*)&packbuf[c0 * 68 + i0 + q * 4];
      *(uint4*)&grow[c0 * 64 + i0 + q * 4] = v;
    }
  }
}

// ---------------- MFMA matmul + bias + residual + LayerNorm (champion verbatim) ----------------
// template<LAST>: last layer fuses the decoder (reads normalized tile from LDS).
template<int LAST>
__global__ __launch_bounds__(256, 4) void mm_mfma_ln_kernel(
    const unsigned int* __restrict__ gp, float* __restrict__ h_buf,
    const unsigned int* __restrict__ Wp, const float* __restrict__ bo,
    const float* __restrict__ lw, const float* __restrict__ lb,
    const float* __restrict__ dcw, const float* __restrict__ dcb,
    float* __restrict__ outp) {
  __shared__ float smem[HH * 33];            // gt (first 32KB); LAST also uses as rt
  __shared__ float red_s[4][BN];
  __shared__ float red_q[4][BN];
  unsigned int* gt = (unsigned int*)smem;
  float* rt = smem;
  int blk = blockIdx.x;
  int b = blk >> 7;
  int l0 = (blk & 127) * BN;
  int t = threadIdx.x;
  const unsigned int* gbase = gp + (size_t)b * HH * LL + l0;
  #pragma unroll
  for (int p = 0; p < 4; ++p) {
    int hh = p * 64 + (t >> 2);
    int lq = (t & 3) * 8;
    const uint4* src = (const uint4*)(gbase + (size_t)hh * LL + lq);
    uint4 v0 = src[0];
    uint4 v1 = src[1];
    unsigned int vals[8] = {v0.x, v0.y, v0.z, v0.w, v1.x, v1.y, v1.z, v1.w};
    #pragma unroll
    for (int j = 0; j < 8; ++j) {
      int l = lq + j;
      int xm = (l & 7) ^ ((l >> 3) & 3);
      int g4 = (hh >> 2) ^ xm;
      gt[l * HH + g4 * 4 + (hh & 3)] = vals[j];
    }
  }
  __syncthreads();
  int wv = t >> 6, lane = t & 63;
  int row16 = lane & 15, kgrp = lane >> 4;
  f32x4 acc[4][2];
  #pragma unroll
  for (int di = 0; di < 4; ++di)
    #pragma unroll
    for (int li = 0; li < 2; ++li)
      acc[di][li] = (f32x4){0.f, 0.f, 0.f, 0.f};
  #pragma unroll 2
  for (int ks = 0; ks < 8; ++ks) {
    int h0 = ks * 32;
    short8 Bhi[2], Blo[2];
    #pragma unroll
    for (int li = 0; li < 2; ++li) {
      int l = li * 16 + row16;
      int xm = (l & 7) ^ ((l >> 3) & 3);
      int g4a = ((h0 >> 2) + kgrp) ^ xm;
      int g4b = ((h0 >> 2) + kgrp + 4) ^ xm;
      uint4 pa = *(const uint4*)&gt[l * HH + g4a * 4];
      uint4 pb = *(const uint4*)&gt[l * HH + g4b * 4];
      union { int i[4]; short8 s; } uh, ul;
      uh.i[0] = (int)((pa.x >> 16) | (pa.y & 0xFFFF0000u));
      uh.i[1] = (int)((pa.z >> 16) | (pa.w & 0xFFFF0000u));
      uh.i[2] = (int)((pb.x >> 16) | (pb.y & 0xFFFF0000u));
      uh.i[3] = (int)((pb.z >> 16) | (pb.w & 0xFFFF0000u));
      ul.i[0] = (int)((pa.x & 0xFFFFu) | (pa.y << 16));
      ul.i[1] = (int)((pa.z & 0xFFFFu) | (pa.w << 16));
      ul.i[2] = (int)((pb.x & 0xFFFFu) | (pb.y << 16));
      ul.i[3] = (int)((pb.z & 0xFFFFu) | (pb.w << 16));
      Bhi[li] = uh.s; Blo[li] = ul.s;
    }
    #pragma unroll
    for (int di = 0; di < 4; ++di) {
      const uint4* wf = (const uint4*)Wp + ((((wv * 8 + ks) * 4 + di) * 64 + lane) * 2);
      uint4 pa = wf[0];
      uint4 pb = wf[1];
      union { int i[4]; short8 s; } uh, ul;
      uh.i[0] = (int)((pa.x >> 16) | (pa.y & 0xFFFF0000u));
      uh.i[1] = (int)((pa.z >> 16) | (pa.w & 0xFFFF0000u));
      uh.i[2] = (int)((pb.x >> 16) | (pb.y & 0xFFFF0000u));
      uh.i[3] = (int)((pb.z >> 16) | (pb.w & 0xFFFF0000u));
      ul.i[0] = (int)((pa.x & 0xFFFFu) | (pa.y << 16));
      ul.i[1] = (int)((pa.z & 0xFFFFu) | (pa.w << 16));
      ul.i[2] = (int)((pb.x & 0xFFFFu) | (pb.y << 16));
      ul.i[3] = (int)((pb.z & 0xFFFFu) | (pb.w << 16));
      short8 Ahi = uh.s, Alo = ul.s;
      #pragma unroll
      for (int li = 0; li < 2; ++li) {
        acc[di][li] = __builtin_amdgcn_mfma_f32_16x16x32_bf16(Ahi, Bhi[li], acc[di][li], 0, 0, 0);
        acc[di][li] = __builtin_amdgcn_mfma_f32_16x16x32_bf16(Ahi, Blo[li], acc[di][li], 0, 0, 0);
        acc[di][li] = __builtin_amdgcn_mfma_f32_16x16x32_bf16(Alo, Bhi[li], acc[di][li], 0, 0, 0);
      }
    }
  }
  const float* hb = h_buf + (size_t)b * HH * LL + l0;
  #pragma unroll
  for (int di = 0; di < 4; ++di) {
    #pragma unroll
    for (int r = 0; r < 4; ++r) {
      int d = wv * 64 + di * 16 + kgrp * 4 + r;
      float bov = bo[d];
      #pragma unroll
      for (int li = 0; li < 2; ++li) {
        int l = li * 16 + row16;
        acc[di][li][r] += bov + hb[(size_t)d * LL + l];
      }
    }
  }
  #pragma unroll
  for (int li = 0; li < 2; ++li) {
    float s = 0.f, q = 0.f;
    #pragma unroll
    for (int di = 0; di < 4; ++di)
      #pragma unroll
      for (int r = 0; r < 4; ++r) {
        float v = acc[di][li][r];
        s += v;
        q = fmaf(v, v, q);
      }
    s += __shfl_xor(s, 16); s += __shfl_xor(s, 32);
    q += __shfl_xor(q, 16); q += __shfl_xor(q, 32);
    if (lane < 16) {
      red_s[wv][li * 16 + lane] = s;
      red_q[wv][li * 16 + lane] = q;
    }
  }
  __syncthreads();   // red visible; also all gt reads complete (K-loop is before)
  float mu[2], rstd[2];
  #pragma unroll
  for (int li = 0; li < 2; ++li) {
    int cl = li * 16 + row16;
    float s = red_s[0][cl] + red_s[1][cl] + red_s[2][cl] + red_s[3][cl];
    float q = red_q[0][cl] + red_q[1][cl] + red_q[2][cl] + red_q[3][cl];
    float m = s * (1.f / 256.f);
    float var = q * (1.f / 256.f) - m * m;
    mu[li] = m;
    rstd[li] = rsqrtf(var + 1e-5f);
  }
  if (!LAST) {
    float* hw = h_buf + (size_t)b * HH * LL + l0;
    #pragma unroll
    for (int di = 0; di < 4; ++di) {
      #pragma unroll
      for (int r = 0; r < 4; ++r) {
        int d = wv * 64 + di * 16 + kgrp * 4 + r;
        float lwv = lw[d], lbv = lb[d];
        #pragma unroll
        for (int li = 0; li < 2; ++li) {
          int l = li * 16 + row16;
          hw[(size_t)d * LL + l] = (acc[di][li][r] - mu[li]) * rstd[li] * lwv + lbv;
        }
      }
    }
  } else {
    // route normalized tile through LDS (gt dead), then fused decoder
    #pragma unroll
    for (int di = 0; di < 4; ++di) {
      #pragma unroll
      for (int r = 0; r < 4; ++r) {
        int d = wv * 64 + di * 16 + kgrp * 4 + r;
        float lwv = lw[d], lbv = lb[d];
        #pragma unroll
        for (int li = 0; li < 2; ++li) {
          int l = li * 16 + row16;
          rt[d * 33 + l] = (acc[di][li][r] - mu[li]) * rstd[li] * lwv + lbv;
        }
      }
    }
    __syncthreads();
    int l = t & 31, dd = t >> 5;   // dd 0..7; thread covers dd and dd+8
    float a0 = dcb[dd], a1 = dcb[dd + 8];
    #pragma unroll 8
    for (int d = 0; d < HH; ++d) {
      float hv = rt[d * 33 + l];
      a0 = fmaf(hv, dcw[d * DIN + dd], a0);
      a1 = fmaf(hv, dcw[d * DIN + dd + 8], a1);
    }
    float* ob = outp + (size_t)b * DIN * LL + l0;
    ob[(size_t)dd * LL + l] = a0;
    ob[(size_t)(dd + 8) * LL + l] = a1;
  }
}

extern "C" void kernel_launch(void* const* d_in, const int* in_sizes, int n_in,
                              void* d_out, int out_size, void* d_ws, size_t ws_size,
                              hipStream_t stream) {
  const float* x      = (const float*)d_in[0];
  const float* enc_w  = (const float*)d_in[1];
  const float* enc_b  = (const float*)d_in[2];
  const float* log_dt = (const float*)d_in[3];
  const float* A_re   = (const float*)d_in[4];
  const float* A_im   = (const float*)d_in[5];
  const float* C_re   = (const float*)d_in[6];
  const float* C_im   = (const float*)d_in[7];
  const float* Dv     = (const float*)d_in[8];
  const float* W_out  = (const float*)d_in[9];
  const float* b_out  = (const float*)d_in[10];
  const float* ln_w   = (const float*)d_in[11];
  const float* ln_b   = (const float*)d_in[12];
  const float* dec_w  = (const float*)d_in[13];
  const float* dec_b  = (const float*)d_in[14];
  float* out = (float*)d_out;

  float* h_buf = (float*)d_ws;
  unsigned int* g_pack = (unsigned int*)(h_buf + (size_t)Bb * HH * LL);
  float* w64 = (float*)(g_pack + (size_t)Bb * HH * LL);
  unsigned int* Wp = (unsigned int*)(w64 + 2 * HN);
  u16* Bf = (u16*)(Wp + HH * HH);

  enc_kernel<<<Bb * HH * (LL / 256), 256, 0, stream>>>(x, enc_w, enc_b, h_buf);
  for (int i = 0; i < NLAY; ++i) {
    prep_kernel<<<2 * HH, 256, 0, stream>>>(log_dt + i * HH, A_re + i * HN,
                                            A_im + i * HN, C_re + i * HN,
                                            C_im + i * HN, w64, Bf,
                                            W_out + (size_t)i * HH * HH, Wp);
    s4_mfma_kernel<<<Bb * HH, 256, 0, stream>>>(h_buf, w64, Dv + i * HH, Bf, g_pack);
    if (i < NLAY - 1) {
      mm_mfma_ln_kernel<0><<<Bb * (LL / BN), 256, 0, stream>>>(
          g_pack, h_buf, Wp, b_out + i * HH, ln_w + i * HH, ln_b + i * HH,
          dec_w, dec_b, out);
    } else {
      mm_mfma_ln_kernel<1><<<Bb * (LL / BN), 256, 0, stream>>>(
          g_pack, h_buf, Wp, b_out + i * HH, ln_w + i * HH, ln_b + i * HH,
          dec_w, dec_b, out);
    }
  }
}